// Round 15
// baseline (233.363 us; speedup 1.0000x reference)
//
#include <hip/hip_runtime.h>
#include <stdint.h>

// Fused attention: q/k/v projections + softmax(QK^T/32 + mask) @ V
// B=4, S=2048, E=1024.
// All GEMMs = R8-proven gemmJ ring-4 structure: 256xBN tile, 8 waves
// (2Mx4N), BK=32, ring-4 LDS (2-barrier slot reuse, R9 ledger), stage-2-
// ahead global_load_lds(16B), counted vmcnt(GPW) gate + ONE barrier per
// K-tile, verified XOR involution swizzle (0 conflicts), setprio,
// bijective XCD swizzle.
// QKV runs at NFRAG=4 (scores-proven geometry, 2.6 GF/s/CU vs 2.0 at N2):
// 384 blocks (~1.5 packed passes) beats gemmF-N2's 130.8us (R12/R14:
// reg-staged fusion refuted — VGPR pressure + tail cancel the cvt saving).
// Softmax eliminated: scores epilogue computes E=exp(x/32+mask) (bounded
// ~e^6), writes E bf16 + atomic row sums; PV epilogue scales by 1/sRow.
//
// ws layout (MB offsets), TIME-MULTIPLEXED (R8/R10-proven):
//   [0,16)   qb        [48, +32KB) sRow (zeroed by cvt7)
//   [16,32)  kb        [80,96)  xq -- dead after proj --+
//   [32,48)  vT        [96,112) xk -- dead after proj   |
//   [80,112) Sb=E  (scores out; aliases xq/xk) <--------+
//   [112,128) xv   [128,130) Wqb  [130,132) Wkb  [132,134) Wvb

typedef __attribute__((ext_vector_type(8))) short s8v;
typedef __attribute__((ext_vector_type(4))) float f32x4;

__device__ __forceinline__ unsigned short f2b(float f) {
  union { float f; unsigned u; } c; c.f = f;
  unsigned r = c.u + 0x7fffu + ((c.u >> 16) & 1u);   // RNE, no NaN inputs
  return (unsigned short)(r >> 16);
}

__device__ __forceinline__ void gload_lds16(const void* gsrc, void* ldst) {
  __builtin_amdgcn_global_load_lds(
      (__attribute__((address_space(1))) unsigned int*)(uintptr_t)gsrc,
      (__attribute__((address_space(3))) unsigned int*)(unsigned)(uintptr_t)ldst,
      16, 0, 0);
}

template <int N> __device__ __forceinline__ void waitvm() {
  if constexpr (N == 4)      asm volatile("s_waitcnt vmcnt(4)" ::: "memory");
  else if constexpr (N == 3) asm volatile("s_waitcnt vmcnt(3)" ::: "memory");
  else                       asm volatile("s_waitcnt vmcnt(0)" ::: "memory");
}

struct Job {
  const unsigned short* A; const unsigned short* B; void* C;
  const float* bias; const float* mask; float* sRow;
  long sAb, sBb, sCb, sMb;
  int lda, ldb, ldc, ldM;
  int K, tilesN, tilesMN;
  float scale; int bmode;    // bias: 0 none, 1 bias[col], 2 bias[row]
};

// NT GEMM: C[m][n] = f(scale*sum_k A[m][k]B[n][k]). M mult of 256, N mult
// of BN=NFRAG*64, K mult of 32. MODE 0: +bias, bf16 out (QKV projections).
// MODE 1: exp(.*scale+mask) -> bf16 out + atomic row sums (scores).
// MODE 2: f32 out * (1/sRow[row]) (PV with normalization).
template <int NFRAG, int MODE>
__global__ __launch_bounds__(512, 2) void gemmJ(Job j0, Job j1, Job j2,
                                                int b0, int b1) {
  constexpr int BN = NFRAG * 64;
  constexpr int ASLOT = 256 * 64;            // bytes: 256 rows x 64B (BK=32)
  constexpr int BSLOT = BN * 64;
  constexpr int SLOT = ASLOT + BSLOT;
  constexpr int CH = SLOT / 1024;            // 1KB chunks per K-tile
  constexpr int GPW = CH / 8;                // gloads per wave per K-tile
  static_assert(4 * SLOT <= 160 * 1024, "LDS budget");
  __shared__ __align__(16) char lds[4 * SLOT];   // ring-4: 2-barrier reuse

  const int nwg = gridDim.x;
  const int hw = blockIdx.x;
  int g = (hw & 7) * (nwg >> 3) + (hw >> 3);   // bijective XCD swizzle (nwg%8==0)
  const Job J = (g < b0) ? j0 : (g < b1) ? j1 : j2;
  g -= (g < b0) ? 0 : (g < b1) ? b0 : b1;

  const int batch = g / J.tilesMN;
  const int tt = g - batch * J.tilesMN;
  const int tm = tt / J.tilesN, tn = tt - tm * J.tilesN;
  const int brow = tm << 8, bcol = tn * BN;

  const int tid = threadIdx.x;
  const int lane = tid & 63, w = tid >> 6;     // 8 waves: 2M x 4N
  const int wm = w >> 2, wn = w & 3;
  const int fr = lane & 15, fq = lane >> 4;

  const unsigned short* Ab = J.A + (long)batch * J.sAb;
  const unsigned short* Bb = J.B + (long)batch * J.sBb;

  // staging: CH 1KB chunks (A first, then B); wave w stages {w, w+8, ...}.
  // LDS dest linear (wave-uniform + lane*16); global source inverse-swizzled
  // so swizzled ds_reads see logical data (rule #21; 0 conflicts, R2-verified).
  const unsigned short* gsrc[GPW];
  int ldsdst[GPW];
#pragma unroll
  for (int i = 0; i < GPW; i++) {
    const int c = w + i * 8;
    const bool isA = (c < 16);
    const int cc = isA ? c : c - 16;
    const int roff = cc * 1024 + lane * 16;          // region-relative linear
    const int L = roff ^ (((roff >> 7) & 7) << 4);   // involution
    const int row = L >> 6, colb = L & 63;
    gsrc[i] = (isA ? (Ab + (long)(brow + row) * J.lda)
                   : (Bb + (long)(bcol + row) * J.ldb)) + (colb >> 1);
    ldsdst[i] = (isA ? 0 : ASLOT) + cc * 1024;
  }

  // ds_read offsets (region-relative, same involution)
  int offA[8], offB[NFRAG];
#pragma unroll
  for (int mi = 0; mi < 8; mi++) {
    const int oa = (wm * 128 + mi * 16 + fr) * 64 + fq * 16;
    offA[mi] = oa ^ (((oa >> 7) & 7) << 4);
  }
#pragma unroll
  for (int ni = 0; ni < NFRAG; ni++) {
    const int ob = (wn * (NFRAG * 16) + ni * 16 + fr) * 64 + fq * 16;
    offB[ni] = ASLOT + (ob ^ (((ob >> 7) & 7) << 4));
  }

  f32x4 acc[8][NFRAG];
#pragma unroll
  for (int mi = 0; mi < 8; mi++)
#pragma unroll
    for (int ni = 0; ni < NFRAG; ni++) acc[mi][ni] = (f32x4){0.f, 0.f, 0.f, 0.f};

  const int NT = J.K >> 5;

#define STAGE(kt) { \
  char* const sb_ = lds + ((kt) & 3) * SLOT; \
  _Pragma("unroll") \
  for (int i_ = 0; i_ < GPW; i_++) \
    gload_lds16(gsrc[i_] + (long)(kt) * 32, sb_ + ldsdst[i_]); }

  // prologue: stage tiles 0,1; tile 0 resident block-wide
  STAGE(0);
  STAGE(1);
  waitvm<GPW>();
  __builtin_amdgcn_s_barrier();

  for (int t = 0; t < NT; ++t) {
    const char* sb = lds + (t & 3) * SLOT;
    if (t + 2 < NT) STAGE(t + 2);            // slot (t+2)&3: last read at t-2

    s8v bf[NFRAG], af[4];
#pragma unroll
    for (int ni = 0; ni < NFRAG; ni++) bf[ni] = *(const s8v*)(sb + offB[ni]);
#pragma unroll
    for (int mi = 0; mi < 4; mi++) af[mi] = *(const s8v*)(sb + offA[mi]);
    __builtin_amdgcn_s_setprio(1);
#pragma unroll
    for (int mi = 0; mi < 4; mi++)
#pragma unroll
      for (int ni = 0; ni < NFRAG; ni++)
        acc[mi][ni] = __builtin_amdgcn_mfma_f32_16x16x32_bf16(
            af[mi], bf[ni], acc[mi][ni], 0, 0, 0);
    __builtin_amdgcn_s_setprio(0);
#pragma unroll
    for (int mi = 0; mi < 4; mi++) af[mi] = *(const s8v*)(sb + offA[4 + mi]);
    __builtin_amdgcn_s_setprio(1);
#pragma unroll
    for (int mi = 0; mi < 4; mi++)
#pragma unroll
      for (int ni = 0; ni < NFRAG; ni++)
        acc[4 + mi][ni] = __builtin_amdgcn_mfma_f32_16x16x32_bf16(
            af[mi], bf[ni], acc[4 + mi][ni], 0, 0, 0);
    __builtin_amdgcn_s_setprio(0);

    if (t + 1 < NT) {
      if (t + 2 < NT) waitvm<GPW>();          // counted: tile t+1 resident
      else            waitvm<0>();            // tail drain
      __builtin_amdgcn_s_barrier();
    }
  }

  // epilogue: C/D frag layout col=lane&15, row=(lane>>4)*4+r  [m89]
  unsigned short* Cb = (unsigned short*)J.C;
  float* Cf = (float*)J.C;
  const long cB = (long)batch * J.sCb;
  const float* maskB = (MODE == 1) ? (J.mask + (long)batch * J.sMb) : nullptr;
  float* sB = (MODE != 0) ? (J.sRow + batch * 2048) : nullptr;

#pragma unroll
  for (int mi = 0; mi < 8; mi++) {
    const int rbase = brow + wm * 128 + mi * 16 + fq * 4;

    if constexpr (MODE == 0) {
#pragma unroll
      for (int ni = 0; ni < NFRAG; ni++) {
        const int col = bcol + wn * (NFRAG * 16) + ni * 16 + fr;
        const float bc = (J.bmode == 1) ? J.bias[col] : 0.f;
#pragma unroll
        for (int r = 0; r < 4; r++) {
          const int row = rbase + r;
          float v = acc[mi][ni][r] + ((J.bmode == 2) ? J.bias[row] : bc);
          Cb[cB + (long)row * J.ldc + col] = f2b(v);
        }
      }
    } else if constexpr (MODE == 1) {
      float rs[4] = {0.f, 0.f, 0.f, 0.f};
#pragma unroll
      for (int ni = 0; ni < NFRAG; ni++) {
        const int col = bcol + wn * (NFRAG * 16) + ni * 16 + fr;
#pragma unroll
        for (int r = 0; r < 4; r++) {
          const int row = rbase + r;
          float v = acc[mi][ni][r] * J.scale + maskB[(long)row * J.ldM + col];
          v = __expf(v);                       // bounded: scores ~N(0,1)
          Cb[cB + (long)row * J.ldc + col] = f2b(v);
          rs[r] += v;
        }
      }
#pragma unroll
      for (int off = 1; off < 16; off <<= 1) {
#pragma unroll
        for (int r = 0; r < 4; r++) rs[r] += __shfl_xor(rs[r], off, 64);
      }
      if (fr == 0) {
#pragma unroll
        for (int r = 0; r < 4; r++) atomicAdd(&sB[rbase + r], rs[r]);
      }
    } else {  // MODE 2: PV, normalize by 1/sRow
      float inv[4];
#pragma unroll
      for (int r = 0; r < 4; r++) inv[r] = 1.0f / sB[rbase + r];
#pragma unroll
      for (int ni = 0; ni < NFRAG; ni++) {
        const int col = bcol + wn * (NFRAG * 16) + ni * 16 + fr;
#pragma unroll
        for (int r = 0; r < 4; r++) {
          const int row = rbase + r;
          Cf[cB + (long)row * J.ldc + col] = acc[mi][ni][r] * inv[r];
        }
      }
    }
  }
#undef STAGE
}

// f32->bf16 for 6 regions + zero sRow. regions 0-2: n8=1048576, 768 blocks
// each; 3-5: n8=131072, 128 blocks each; blocks 2688-2695 zero sRow[8192].
__global__ __launch_bounds__(256) void cvt7(
    const float* s0, unsigned short* d0, const float* s1, unsigned short* d1,
    const float* s2, unsigned short* d2, const float* s3, unsigned short* d3,
    const float* s4, unsigned short* d4, const float* s5, unsigned short* d5,
    float* sz) {
  int bid = blockIdx.x;
  if (bid >= 2688) {
    for (int i = (bid - 2688) * 256 + threadIdx.x; i < 8192; i += 2048)
      sz[i] = 0.f;
    return;
  }
  const float* src; unsigned short* dst; long n8; int lb, nb;
  if (bid < 2304) {
    int r = bid / 768; lb = bid - r * 768; nb = 768; n8 = 1048576;
    src = r == 0 ? s0 : r == 1 ? s1 : s2;
    dst = r == 0 ? d0 : r == 1 ? d1 : d2;
  } else {
    int r = (bid - 2304) / 128; lb = (bid - 2304) - r * 128; nb = 128; n8 = 131072;
    src = r == 0 ? s3 : r == 1 ? s4 : s5;
    dst = r == 0 ? d3 : r == 1 ? d4 : d5;
  }
  const long stride = (long)nb * 256;
  for (long i = (long)lb * 256 + threadIdx.x; i < n8; i += stride) {
    const float* p = src + i * 8;
    f32x4 va = *(const f32x4*)p;
    f32x4 vb = *(const f32x4*)(p + 4);
    s8v o;
    o[0] = (short)f2b(va[0]); o[1] = (short)f2b(va[1]);
    o[2] = (short)f2b(va[2]); o[3] = (short)f2b(va[3]);
    o[4] = (short)f2b(vb[0]); o[5] = (short)f2b(vb[1]);
    o[6] = (short)f2b(vb[2]); o[7] = (short)f2b(vb[3]);
    *(s8v*)(dst + i * 8) = o;
  }
}

extern "C" void kernel_launch(void* const* d_in, const int* in_sizes, int n_in,
                              void* d_out, int out_size, void* d_ws, size_t ws_size,
                              hipStream_t stream) {
  const float* q    = (const float*)d_in[0];
  const float* k    = (const float*)d_in[1];
  const float* v    = (const float*)d_in[2];
  const float* mask = (const float*)d_in[3];
  const float* Wq   = (const float*)d_in[4];
  const float* bq   = (const float*)d_in[5];
  const float* Wk   = (const float*)d_in[6];
  const float* bk   = (const float*)d_in[7];
  const float* Wv   = (const float*)d_in[8];
  const float* bv   = (const float*)d_in[9];
  float* out = (float*)d_out;

  const size_t MB = 1ull << 20;
  if (ws_size < 134 * MB) return;
  char* ws = (char*)d_ws;
  unsigned short* qb  = (unsigned short*)(ws + 0 * MB);
  unsigned short* kb  = (unsigned short*)(ws + 16 * MB);
  unsigned short* vT  = (unsigned short*)(ws + 32 * MB);
  float*          sRw = (float*)(ws + 48 * MB);           // 32KB, own region
  unsigned short* Sb  = (unsigned short*)(ws + 80 * MB);  // aliases xq+xk
  unsigned short* xq  = (unsigned short*)(ws + 80 * MB);
  unsigned short* xk  = (unsigned short*)(ws + 96 * MB);
  unsigned short* xv  = (unsigned short*)(ws + 112 * MB);
  unsigned short* Wqb = (unsigned short*)(ws + 128 * MB);
  unsigned short* Wkb = (unsigned short*)(ws + 130 * MB);
  unsigned short* Wvb = (unsigned short*)(ws + 132 * MB);

  cvt7<<<2696, 256, 0, stream>>>(q, xq, k, xk, v, xv, Wq, Wqb, Wk, Wkb, Wv, Wvb,
                                 sRw);

  // QKV projections at NFRAG=4 (scores-proven geometry), one 384-block
  // launch: q 32tm x 4tn = 128; k 128; v (A=Wv M=1024: 4tm x 8tn x 4b) 128.
  Job jq = { xq, Wqb, (void*)qb, bq, nullptr, nullptr, 0, 0, 0, 0,
             1024, 1024, 1024, 0, 1024, 4, 128, 1.0f, 1 };
  Job jk = { xk, Wkb, (void*)kb, bk, nullptr, nullptr, 0, 0, 0, 0,
             1024, 1024, 1024, 0, 1024, 4, 128, 1.0f, 1 };
  Job jv = { Wvb, xv, (void*)vT, bv, nullptr, nullptr, 0, 2048L * 1024,
             1024L * 2048, 0, 1024, 1024, 2048, 0, 1024, 8, 32, 1.0f, 2 };
  gemmJ<4, 0><<<384, 512, 0, stream>>>(jq, jk, jv, 128, 256);

  // scores -> E = exp(qk/32 + mask), bf16, + row sums. 8x8x4 = 256 blocks.
  // Writes Sb over the (now dead) xq/xk region.
  Job js = { qb, kb, (void*)Sb, nullptr, mask, sRw,
             2048L * 1024, 2048L * 1024, 2048L * 2048, 2048L * 2048,
             1024, 1024, 2048, 2048, 1024, 8, 64, 0.03125f, 0 };
  gemmJ<4, 1><<<256, 512, 0, stream>>>(js, js, js, 256, 256);

  // PV: out = (E . vT^T) / sRow; 8 tm x 8 tn x 4 = 256 blocks, K=2048.
  Job jp = { Sb, vT, (void*)out, nullptr, nullptr, sRw,
             2048L * 2048, 1024L * 2048, 2048L * 1024, 0,
             2048, 2048, 1024, 0, 2048, 8, 64, 1.0f, 0 };
  gemmJ<2, 2><<<256, 512, 0, stream>>>(jp, jp, jp, 256, 256);
}

// Round 16
// 220.927 us; speedup vs baseline: 1.0563x; 1.0563x over previous
//
#include <hip/hip_runtime.h>
#include <stdint.h>

// Fused attention: q/k/v projections + softmax(QK^T/32 + mask) @ V
// B=4, S=2048, E=1024.
// gemmF (QKV from raw f32): R12-proven reg-staged pipeline (2-iteration
// lead, v_cvt_pk_bf16_f32 + ds_write, one lgkmcnt(0)+barrier per tile),
// now RING-3 LDS (72KB -> 2 blocks/CU; R13 proved ring-3+ds_write correct;
// R9's ring-3 race was gload_lds-async-specific). Slot reuse distance = 2
// barriers (hand-traced; meets R9 ledger rule).
// gemmJ (scores/PV) = R8-proven ring-4 BK=32 gload_lds structure.
// Softmax eliminated: scores epilogue computes E=exp(x/32+mask) (bounded
// ~e^6), writes E bf16 + atomic row sums; PV epilogue scales by 1/sRow.
//
// ws layout (MB offsets): [0,16) qb / [16,32) kb / [32,48) vT /
// [48,+32KB) sRow / [80,112) Sb=E.

typedef __attribute__((ext_vector_type(8))) short s8v;
typedef __attribute__((ext_vector_type(4))) float f32x4;
typedef __attribute__((ext_vector_type(4))) unsigned u32x4;

__device__ __forceinline__ unsigned short f2b(float f) {
  union { float f; unsigned u; } c; c.f = f;
  unsigned r = c.u + 0x7fffu + ((c.u >> 16) & 1u);   // RNE, no NaN inputs
  return (unsigned short)(r >> 16);
}

__device__ __forceinline__ void gload_lds16(const void* gsrc, void* ldst) {
  __builtin_amdgcn_global_load_lds(
      (__attribute__((address_space(1))) unsigned int*)(uintptr_t)gsrc,
      (__attribute__((address_space(3))) unsigned int*)(unsigned)(uintptr_t)ldst,
      16, 0, 0);
}

template <int N> __device__ __forceinline__ void waitvm() {
  if constexpr (N == 4)      asm volatile("s_waitcnt vmcnt(4)" ::: "memory");
  else if constexpr (N == 3) asm volatile("s_waitcnt vmcnt(3)" ::: "memory");
  else                       asm volatile("s_waitcnt vmcnt(0)" ::: "memory");
}

// ---------------- gemmF: QKV projection from f32 sources ----------------
struct JobF {
  const float* A; const float* B; unsigned short* C; const float* bias;
  long sAb, sBb, sCb;
  int lda, ldb, ldc, tilesN, tilesMN, bmode;   // bias: 1=col, 2=row
};

// NT GEMM from f32: C[m][n] = bf16(sum_k A[m][k]B[n][k] + bias). 256x128
// tile, 8 waves (2Mx4N), BK=32, K=1024 fixed (NT=32), RING-3 LDS (72KB,
// 2 blocks/CU), reg-staged f32 with 2-iter lead + v_cvt_pk_bf16_f32.
__global__ __launch_bounds__(512, 2) void gemmF(JobF j0, JobF j1, JobF j2,
                                                int b0, int b1) {
  constexpr int ASLOT = 256 * 64;       // bf16 bytes (256 rows x 64B, BK=32)
  constexpr int SLOT = ASLOT + 128 * 64;
  constexpr int NT = 32;                // K=1024
  __shared__ __align__(16) char lds[3 * SLOT];   // ring-3: 72KB

  const int nwg = gridDim.x;
  const int hw = blockIdx.x;
  int g = (hw & 7) * (nwg >> 3) + (hw >> 3);
  const JobF J = (g < b0) ? j0 : (g < b1) ? j1 : j2;
  g -= (g < b0) ? 0 : (g < b1) ? b0 : b1;

  const int batch = g / J.tilesMN;
  const int tt = g - batch * J.tilesMN;
  const int tm = tt / J.tilesN, tn = tt - tm * J.tilesN;
  const int brow = tm << 8, bcol = tn << 7;

  const int tid = threadIdx.x, lane = tid & 63, w = tid >> 6;
  const int wm = w >> 2, wn = w & 3;
  const int fr = lane & 15, fq = lane >> 4;

  const float* Ab = J.A + (long)batch * J.sAb;
  const float* Bb = J.B + (long)batch * J.sBb;

  // 24 1KB-bf16 chunks/K-tile (A:0-15, B:16-23); wave w owns {w,w+8,w+16}.
  // Source index inverse-swizzled (same involution as ds_read side).
  const float* gsrcF[3];
  int ldsdst[3];
#pragma unroll
  for (int i = 0; i < 3; i++) {
    const int c = w + i * 8;
    const bool isA = (c < 16);
    const int cc = isA ? c : c - 16;
    const int roff = cc * 1024 + lane * 16;
    const int L = roff ^ (((roff >> 7) & 7) << 4);
    const int row = L >> 6, elem = (L & 63) >> 1;   // logical f32 elem
    gsrcF[i] = (isA ? (Ab + (long)(brow + row) * J.lda)
                    : (Bb + (long)(bcol + row) * J.ldb)) + elem;
    ldsdst[i] = (isA ? 0 : ASLOT) + cc * 1024 + lane * 16;
  }

  int offA[8], offB[2];
#pragma unroll
  for (int mi = 0; mi < 8; mi++) {
    const int oa = (wm * 128 + mi * 16 + fr) * 64 + fq * 16;
    offA[mi] = oa ^ (((oa >> 7) & 7) << 4);
  }
#pragma unroll
  for (int ni = 0; ni < 2; ni++) {
    const int ob = (wn * 32 + ni * 16 + fr) * 64 + fq * 16;
    offB[ni] = ASLOT + (ob ^ (((ob >> 7) & 7) << 4));
  }

  f32x4 acc[8][2];
#pragma unroll
  for (int mi = 0; mi < 8; mi++)
#pragma unroll
    for (int ni = 0; ni < 2; ni++) acc[mi][ni] = (f32x4){0.f, 0.f, 0.f, 0.f};

  f32x4 eLo[3], eHi[3], oLo[3], oHi[3];   // set0 = even tiles, set1 = odd

#define SLOT3(x) (((x) % 3) * SLOT)

#define ISSUE(kt, LO, HI) { \
  _Pragma("unroll") \
  for (int i_ = 0; i_ < 3; i_++) { \
    const float* p_ = gsrcF[i_] + (long)(kt) * 32; \
    LO[i_] = *(const f32x4*)p_; HI[i_] = *(const f32x4*)(p_ + 4); } }

#define CVTWRITE(kt, LO, HI) { \
  char* const sb_ = lds + SLOT3(kt); \
  _Pragma("unroll") \
  for (int i_ = 0; i_ < 3; i_++) { \
    unsigned o0_, o1_, o2_, o3_; \
    asm("v_cvt_pk_bf16_f32 %0, %1, %2" : "=v"(o0_) : "v"(LO[i_][0]), "v"(LO[i_][1])); \
    asm("v_cvt_pk_bf16_f32 %0, %1, %2" : "=v"(o1_) : "v"(LO[i_][2]), "v"(LO[i_][3])); \
    asm("v_cvt_pk_bf16_f32 %0, %1, %2" : "=v"(o2_) : "v"(HI[i_][0]), "v"(HI[i_][1])); \
    asm("v_cvt_pk_bf16_f32 %0, %1, %2" : "=v"(o3_) : "v"(HI[i_][2]), "v"(HI[i_][3])); \
    *(u32x4*)(sb_ + ldsdst[i_]) = (u32x4){o0_, o1_, o2_, o3_}; } }

#define MFMA_BODY(t) { \
  const char* sb_ = lds + SLOT3(t); \
  s8v bf_[2], af_[4]; \
  _Pragma("unroll") \
  for (int ni_ = 0; ni_ < 2; ni_++) bf_[ni_] = *(const s8v*)(sb_ + offB[ni_]); \
  _Pragma("unroll") \
  for (int mi_ = 0; mi_ < 4; mi_++) af_[mi_] = *(const s8v*)(sb_ + offA[mi_]); \
  __builtin_amdgcn_s_setprio(1); \
  _Pragma("unroll") \
  for (int mi_ = 0; mi_ < 4; mi_++) \
    _Pragma("unroll") \
    for (int ni_ = 0; ni_ < 2; ni_++) \
      acc[mi_][ni_] = __builtin_amdgcn_mfma_f32_16x16x32_bf16( \
          af_[mi_], bf_[ni_], acc[mi_][ni_], 0, 0, 0); \
  __builtin_amdgcn_s_setprio(0); \
  _Pragma("unroll") \
  for (int mi_ = 0; mi_ < 4; mi_++) af_[mi_] = *(const s8v*)(sb_ + offA[4 + mi_]); \
  __builtin_amdgcn_s_setprio(1); \
  _Pragma("unroll") \
  for (int mi_ = 0; mi_ < 4; mi_++) \
    _Pragma("unroll") \
    for (int ni_ = 0; ni_ < 2; ni_++) \
      acc[4 + mi_][ni_] = __builtin_amdgcn_mfma_f32_16x16x32_bf16( \
          af_[mi_], bf_[ni_], acc[4 + mi_][ni_], 0, 0, 0); \
  __builtin_amdgcn_s_setprio(0); }

#define ENDBAR() { \
  asm volatile("s_waitcnt lgkmcnt(0)" ::: "memory"); \
  __builtin_amdgcn_s_barrier(); }

  // prologue (R12-proven): tile k -> set[k&1].
  ISSUE(0, eLo, eHi);       // tile 0 -> set0
  ISSUE(1, oLo, oHi);       // tile 1 -> set1
  CVTWRITE(0, eLo, eHi);    // slot 0 (vmcnt auto-waited via reg deps)
  ENDBAR();
  ISSUE(2, eLo, eHi);       // tile 2 -> set0 (freed)

  // invariant at iter t: slot t%3 ready; set[(t+1)&1] holds tile t+1's f32
  // (issued at iter t-2 => ~2 iterations of latency cover); ISSUE(t+2) in
  // flight. Ring-3: slot (t+1)%3 written at t, last read at t-2 =>
  // 2-barrier reuse distance (ds_write ordered by asm memory clobber;
  // R13 empirically validated ring-3 + ds_write staging).
  for (int t = 0; t < NT; t += 2) {
    MFMA_BODY(t);
    if (t + 1 < NT) {
      CVTWRITE(t + 1, oLo, oHi);
      if (t + 3 < NT) ISSUE(t + 3, oLo, oHi);
      ENDBAR();
      MFMA_BODY(t + 1);
      if (t + 2 < NT) {
        CVTWRITE(t + 2, eLo, eHi);
        if (t + 4 < NT) ISSUE(t + 4, eLo, eHi);
        ENDBAR();
      }
    }
  }

  // epilogue: C/D frag layout col=lane&15, row=(lane>>4)*4+r  [m89]
  const long cB = (long)batch * J.sCb;
#pragma unroll
  for (int mi = 0; mi < 8; mi++) {
    const int rbase = brow + wm * 128 + mi * 16 + fq * 4;
#pragma unroll
    for (int ni = 0; ni < 2; ni++) {
      const int col = bcol + wn * 32 + ni * 16 + fr;
      const float bc = (J.bmode == 1) ? J.bias[col] : 0.f;
#pragma unroll
      for (int r = 0; r < 4; r++) {
        const int row = rbase + r;
        float v = acc[mi][ni][r] + ((J.bmode == 2) ? J.bias[row] : bc);
        J.C[cB + (long)row * J.ldc + col] = f2b(v);
      }
    }
  }
#undef ISSUE
#undef CVTWRITE
#undef MFMA_BODY
#undef ENDBAR
#undef SLOT3
}

// ---------------- gemmJ: bf16-source GEMM (scores / PV), R8-proven -------
struct Job {
  const unsigned short* A; const unsigned short* B; void* C;
  const float* bias; const float* mask; float* sRow;
  long sAb, sBb, sCb, sMb;
  int lda, ldb, ldc, ldM;
  int K, tilesN, tilesMN;
  float scale; int bmode;
};

// MODE 1: exp(.*scale+mask) -> bf16 out + atomic row sums (scores).
// MODE 2: f32 out * (1/sRow[row]) (PV with normalization).
template <int NFRAG, int MODE>
__global__ __launch_bounds__(512, 2) void gemmJ(Job j0, Job j1, Job j2,
                                                int b0, int b1) {
  constexpr int BN = NFRAG * 64;
  constexpr int ASLOT = 256 * 64;
  constexpr int BSLOT = BN * 64;
  constexpr int SLOT = ASLOT + BSLOT;
  constexpr int CH = SLOT / 1024;
  constexpr int GPW = CH / 8;
  static_assert(4 * SLOT <= 160 * 1024, "LDS budget");
  __shared__ __align__(16) char lds[4 * SLOT];   // ring-4: 2-barrier reuse

  const int nwg = gridDim.x;
  const int hw = blockIdx.x;
  int g = (hw & 7) * (nwg >> 3) + (hw >> 3);
  const Job J = (g < b0) ? j0 : (g < b1) ? j1 : j2;
  g -= (g < b0) ? 0 : (g < b1) ? b0 : b1;

  const int batch = g / J.tilesMN;
  const int tt = g - batch * J.tilesMN;
  const int tm = tt / J.tilesN, tn = tt - tm * J.tilesN;
  const int brow = tm << 8, bcol = tn * BN;

  const int tid = threadIdx.x;
  const int lane = tid & 63, w = tid >> 6;
  const int wm = w >> 2, wn = w & 3;
  const int fr = lane & 15, fq = lane >> 4;

  const unsigned short* Ab = J.A + (long)batch * J.sAb;
  const unsigned short* Bb = J.B + (long)batch * J.sBb;

  const unsigned short* gsrc[GPW];
  int ldsdst[GPW];
#pragma unroll
  for (int i = 0; i < GPW; i++) {
    const int c = w + i * 8;
    const bool isA = (c < 16);
    const int cc = isA ? c : c - 16;
    const int roff = cc * 1024 + lane * 16;
    const int L = roff ^ (((roff >> 7) & 7) << 4);
    const int row = L >> 6, colb = L & 63;
    gsrc[i] = (isA ? (Ab + (long)(brow + row) * J.lda)
                   : (Bb + (long)(bcol + row) * J.ldb)) + (colb >> 1);
    ldsdst[i] = (isA ? 0 : ASLOT) + cc * 1024;
  }

  int offA[8], offB[NFRAG];
#pragma unroll
  for (int mi = 0; mi < 8; mi++) {
    const int oa = (wm * 128 + mi * 16 + fr) * 64 + fq * 16;
    offA[mi] = oa ^ (((oa >> 7) & 7) << 4);
  }
#pragma unroll
  for (int ni = 0; ni < NFRAG; ni++) {
    const int ob = (wn * (NFRAG * 16) + ni * 16 + fr) * 64 + fq * 16;
    offB[ni] = ASLOT + (ob ^ (((ob >> 7) & 7) << 4));
  }

  f32x4 acc[8][NFRAG];
#pragma unroll
  for (int mi = 0; mi < 8; mi++)
#pragma unroll
    for (int ni = 0; ni < NFRAG; ni++) acc[mi][ni] = (f32x4){0.f, 0.f, 0.f, 0.f};

  const int NT = J.K >> 5;

#define STAGE(kt) { \
  char* const sb_ = lds + ((kt) & 3) * SLOT; \
  _Pragma("unroll") \
  for (int i_ = 0; i_ < GPW; i_++) \
    gload_lds16(gsrc[i_] + (long)(kt) * 32, sb_ + ldsdst[i_]); }

  STAGE(0);
  STAGE(1);
  waitvm<GPW>();
  __builtin_amdgcn_s_barrier();

  for (int t = 0; t < NT; ++t) {
    const char* sb = lds + (t & 3) * SLOT;
    if (t + 2 < NT) STAGE(t + 2);

    s8v bf[NFRAG], af[4];
#pragma unroll
    for (int ni = 0; ni < NFRAG; ni++) bf[ni] = *(const s8v*)(sb + offB[ni]);
#pragma unroll
    for (int mi = 0; mi < 4; mi++) af[mi] = *(const s8v*)(sb + offA[mi]);
    __builtin_amdgcn_s_setprio(1);
#pragma unroll
    for (int mi = 0; mi < 4; mi++)
#pragma unroll
      for (int ni = 0; ni < NFRAG; ni++)
        acc[mi][ni] = __builtin_amdgcn_mfma_f32_16x16x32_bf16(
            af[mi], bf[ni], acc[mi][ni], 0, 0, 0);
    __builtin_amdgcn_s_setprio(0);
#pragma unroll
    for (int mi = 0; mi < 4; mi++) af[mi] = *(const s8v*)(sb + offA[4 + mi]);
    __builtin_amdgcn_s_setprio(1);
#pragma unroll
    for (int mi = 0; mi < 4; mi++)
#pragma unroll
      for (int ni = 0; ni < NFRAG; ni++)
        acc[4 + mi][ni] = __builtin_amdgcn_mfma_f32_16x16x32_bf16(
            af[mi], bf[ni], acc[4 + mi][ni], 0, 0, 0);
    __builtin_amdgcn_s_setprio(0);

    if (t + 1 < NT) {
      if (t + 2 < NT) waitvm<GPW>();
      else            waitvm<0>();
      __builtin_amdgcn_s_barrier();
    }
  }

  unsigned short* Cb = (unsigned short*)J.C;
  float* Cf = (float*)J.C;
  const long cB = (long)batch * J.sCb;
  const float* maskB = (MODE == 1) ? (J.mask + (long)batch * J.sMb) : nullptr;
  float* sB = (J.sRow != nullptr) ? (J.sRow + batch * 2048) : nullptr;

#pragma unroll
  for (int mi = 0; mi < 8; mi++) {
    const int rbase = brow + wm * 128 + mi * 16 + fq * 4;

    if constexpr (MODE == 1) {
      float rs[4] = {0.f, 0.f, 0.f, 0.f};
#pragma unroll
      for (int ni = 0; ni < NFRAG; ni++) {
        const int col = bcol + wn * (NFRAG * 16) + ni * 16 + fr;
#pragma unroll
        for (int r = 0; r < 4; r++) {
          const int row = rbase + r;
          float v = acc[mi][ni][r] * J.scale + maskB[(long)row * J.ldM + col];
          v = __expf(v);
          Cb[cB + (long)row * J.ldc + col] = f2b(v);
          rs[r] += v;
        }
      }
#pragma unroll
      for (int off = 1; off < 16; off <<= 1) {
#pragma unroll
        for (int r = 0; r < 4; r++) rs[r] += __shfl_xor(rs[r], off, 64);
      }
      if (fr == 0) {
#pragma unroll
        for (int r = 0; r < 4; r++) atomicAdd(&sB[rbase + r], rs[r]);
      }
    } else {  // MODE 2: PV, normalize by 1/sRow
      float inv[4];
#pragma unroll
      for (int r = 0; r < 4; r++) inv[r] = 1.0f / sB[rbase + r];
#pragma unroll
      for (int ni = 0; ni < NFRAG; ni++) {
        const int col = bcol + wn * (NFRAG * 16) + ni * 16 + fr;
#pragma unroll
        for (int r = 0; r < 4; r++) {
          const int row = rbase + r;
          Cf[cB + (long)row * J.ldc + col] = acc[mi][ni][r] * inv[r];
        }
      }
    }
  }
#undef STAGE
}

// zero sRow[8192]
__global__ __launch_bounds__(256) void zeroS(float* sz) {
  sz[blockIdx.x * 256 + threadIdx.x] = 0.f;
}

extern "C" void kernel_launch(void* const* d_in, const int* in_sizes, int n_in,
                              void* d_out, int out_size, void* d_ws, size_t ws_size,
                              hipStream_t stream) {
  const float* q    = (const float*)d_in[0];
  const float* k    = (const float*)d_in[1];
  const float* v    = (const float*)d_in[2];
  const float* mask = (const float*)d_in[3];
  const float* Wq   = (const float*)d_in[4];
  const float* bq   = (const float*)d_in[5];
  const float* Wk   = (const float*)d_in[6];
  const float* bk   = (const float*)d_in[7];
  const float* Wv   = (const float*)d_in[8];
  const float* bv   = (const float*)d_in[9];
  float* out = (float*)d_out;

  const size_t MB = 1ull << 20;
  if (ws_size < 134 * MB) return;
  char* ws = (char*)d_ws;
  unsigned short* qb  = (unsigned short*)(ws + 0 * MB);
  unsigned short* kb  = (unsigned short*)(ws + 16 * MB);
  unsigned short* vT  = (unsigned short*)(ws + 32 * MB);
  float*          sRw = (float*)(ws + 48 * MB);           // 32KB
  unsigned short* Sb  = (unsigned short*)(ws + 80 * MB);  // 32MB

  zeroS<<<32, 256, 0, stream>>>(sRw);

  // QKV fused from raw f32 (768 blocks): q-proj 256 (32 tm x 8 tn),
  // k-proj 256, v-proj transposed 256 (A=Wv M=1024: 4 tm x 16 tn x 4 b).
  JobF fq = { q, Wq, qb, bq, 0, 0, 0, 1024, 1024, 1024, 8, 256, 1 };
  JobF fk = { k, Wk, kb, bk, 0, 0, 0, 1024, 1024, 1024, 8, 256, 1 };
  JobF fv = { Wv, v, vT, bv, 0, 2048L * 1024, 1024L * 2048,
              1024, 1024, 2048, 16, 64, 2 };
  gemmF<<<768, 512, 0, stream>>>(fq, fk, fv, 256, 512);

  // scores -> E = exp(qk/32 + mask), bf16, + row sums. 8x8x4 = 256 blocks.
  Job js = { qb, kb, (void*)Sb, nullptr, mask, sRw,
             2048L * 1024, 2048L * 1024, 2048L * 2048, 2048L * 2048,
             1024, 1024, 2048, 2048, 1024, 8, 64, 0.03125f, 0 };
  gemmJ<4, 1><<<256, 512, 0, stream>>>(js, js, js, 256, 256);

  // PV: out = (E . vT^T) / sRow; 8 tm x 8 tn x 4 = 256 blocks, K=2048.
  Job jp = { Sb, vT, (void*)out, nullptr, nullptr, sRw,
             2048L * 2048, 1024L * 2048, 2048L * 1024, 0,
             2048, 2048, 1024, 0, 2048, 8, 64, 1.0f, 0 };
  gemmJ<2, 2><<<256, 512, 0, stream>>>(jp, jp, jp, 256, 256);
}

// Round 17
// 219.521 us; speedup vs baseline: 1.0631x; 1.0064x over previous
//
#include <hip/hip_runtime.h>
#include <stdint.h>

// Fused attention: q/k/v projections + softmax(QK^T/32 + mask) @ V
// B=4, S=2048, E=1024.
// gemmF (QKV from raw f32): 256x256 tile (NFRAG=4: 375B LDS-read/MFMA vs
// 640 at NFRAG=2 — R16 A/B proved LDS-pipe-bound, TLP null), BK=32, ring-4
// LDS (128KB), SINGLE staging reg set (R14's two-set 192+VGPR squeeze ->
// spills; single set = acc128+stage32+addr ~190, no spill at (512,1)),
// R13-proven 1-iteration-lead schedule: MFMA(t) -> CVTWRITE(t+1) ->
// ISSUE(t+2) -> lgkmcnt(0)+barrier. Slot reuse distance 4 barriers.
// gemmJ (scores/PV) = R8-proven ring-4 BK=32 gload_lds structure.
// Softmax eliminated: scores epilogue computes E=exp(x/32+mask) (bounded
// ~e^6), writes E bf16 + atomic row sums; PV epilogue scales by 1/sRow.
//
// ws layout (MB offsets): [0,16) qb / [16,32) kb / [32,48) vT /
// [48,+32KB) sRow / [80,112) Sb=E.

typedef __attribute__((ext_vector_type(8))) short s8v;
typedef __attribute__((ext_vector_type(4))) float f32x4;
typedef __attribute__((ext_vector_type(4))) unsigned u32x4;

__device__ __forceinline__ unsigned short f2b(float f) {
  union { float f; unsigned u; } c; c.f = f;
  unsigned r = c.u + 0x7fffu + ((c.u >> 16) & 1u);   // RNE, no NaN inputs
  return (unsigned short)(r >> 16);
}

__device__ __forceinline__ void gload_lds16(const void* gsrc, void* ldst) {
  __builtin_amdgcn_global_load_lds(
      (__attribute__((address_space(1))) unsigned int*)(uintptr_t)gsrc,
      (__attribute__((address_space(3))) unsigned int*)(unsigned)(uintptr_t)ldst,
      16, 0, 0);
}

template <int N> __device__ __forceinline__ void waitvm() {
  if constexpr (N == 4)      asm volatile("s_waitcnt vmcnt(4)" ::: "memory");
  else if constexpr (N == 3) asm volatile("s_waitcnt vmcnt(3)" ::: "memory");
  else                       asm volatile("s_waitcnt vmcnt(0)" ::: "memory");
}

// ---------------- gemmF: QKV projection from f32 sources ----------------
struct JobF {
  const float* A; const float* B; unsigned short* C; const float* bias;
  long sAb, sBb, sCb;
  int lda, ldb, ldc, tilesN, tilesMN, bmode;   // bias: 1=col, 2=row
};

// NT GEMM from f32: C[m][n] = bf16(sum_k A[m][k]B[n][k] + bias). 256x256
// tile, 8 waves (2Mx4N, per-wave 128x64), BK=32, K=1024 fixed (NT=32),
// ring-4 LDS, single-set reg staging + v_cvt_pk_bf16_f32 + ds_write.
__global__ __launch_bounds__(512, 1) void gemmF(JobF j0, JobF j1, JobF j2,
                                                int b0, int b1) {
  constexpr int ASLOT = 256 * 64;       // bf16 bytes (256 rows x 64B, BK=32)
  constexpr int SLOT = 2 * ASLOT;       // + B: 256 rows x 64B
  constexpr int NT = 32;                // K=1024
  __shared__ __align__(16) char lds[4 * SLOT];   // 128KB

  const int nwg = gridDim.x;
  const int hw = blockIdx.x;
  int g = (hw & 7) * (nwg >> 3) + (hw >> 3);
  const JobF J = (g < b0) ? j0 : (g < b1) ? j1 : j2;
  g -= (g < b0) ? 0 : (g < b1) ? b0 : b1;

  const int batch = g / J.tilesMN;
  const int tt = g - batch * J.tilesMN;
  const int tm = tt / J.tilesN, tn = tt - tm * J.tilesN;
  const int brow = tm << 8, bcol = tn << 8;

  const int tid = threadIdx.x, lane = tid & 63, w = tid >> 6;
  const int wm = w >> 2, wn = w & 3;
  const int fr = lane & 15, fq = lane >> 4;

  const float* Ab = J.A + (long)batch * J.sAb;
  const float* Bb = J.B + (long)batch * J.sBb;

  // 32 1KB-bf16 chunks/K-tile (A:0-15, B:16-31); wave w owns {w+8i, i<4}.
  // 64B rows; swizzle byte^=((byte>>7)&7)<<4 (involution); src inverse-swz.
  const float* gsrcF[4];
  int ldsdst[4];
#pragma unroll
  for (int i = 0; i < 4; i++) {
    const int c = w + i * 8;
    const bool isA = (c < 16);
    const int cc = isA ? c : c - 16;
    const int roff = cc * 1024 + lane * 16;
    const int L = roff ^ (((roff >> 7) & 7) << 4);
    const int row = L >> 6, elem = (L & 63) >> 1;   // logical f32 elem
    gsrcF[i] = (isA ? (Ab + (long)(brow + row) * J.lda)
                    : (Bb + (long)(bcol + row) * J.ldb)) + elem;
    ldsdst[i] = (isA ? 0 : ASLOT) + cc * 1024 + lane * 16;
  }

  int offA[8], offB[4];
#pragma unroll
  for (int mi = 0; mi < 8; mi++) {
    const int oa = (wm * 128 + mi * 16 + fr) * 64 + fq * 16;
    offA[mi] = oa ^ (((oa >> 7) & 7) << 4);
  }
#pragma unroll
  for (int ni = 0; ni < 4; ni++) {
    const int ob = (wn * 64 + ni * 16 + fr) * 64 + fq * 16;
    offB[ni] = ASLOT + (ob ^ (((ob >> 7) & 7) << 4));
  }

  f32x4 acc[8][4];
#pragma unroll
  for (int mi = 0; mi < 8; mi++)
#pragma unroll
    for (int ni = 0; ni < 4; ni++) acc[mi][ni] = (f32x4){0.f, 0.f, 0.f, 0.f};

  f32x4 sLo[4], sHi[4];                 // SINGLE staging set (32 VGPR)

#define ISSUE(kt) { \
  _Pragma("unroll") \
  for (int i_ = 0; i_ < 4; i_++) { \
    const float* p_ = gsrcF[i_] + (long)(kt) * 32; \
    sLo[i_] = *(const f32x4*)p_; sHi[i_] = *(const f32x4*)(p_ + 4); } }

#define CVTWRITE(kt) { \
  char* const sb_ = lds + ((kt) & 3) * SLOT; \
  _Pragma("unroll") \
  for (int i_ = 0; i_ < 4; i_++) { \
    unsigned o0_, o1_, o2_, o3_; \
    asm("v_cvt_pk_bf16_f32 %0, %1, %2" : "=v"(o0_) : "v"(sLo[i_][0]), "v"(sLo[i_][1])); \
    asm("v_cvt_pk_bf16_f32 %0, %1, %2" : "=v"(o1_) : "v"(sLo[i_][2]), "v"(sLo[i_][3])); \
    asm("v_cvt_pk_bf16_f32 %0, %1, %2" : "=v"(o2_) : "v"(sHi[i_][0]), "v"(sHi[i_][1])); \
    asm("v_cvt_pk_bf16_f32 %0, %1, %2" : "=v"(o3_) : "v"(sHi[i_][2]), "v"(sHi[i_][3])); \
    *(u32x4*)(sb_ + ldsdst[i_]) = (u32x4){o0_, o1_, o2_, o3_}; } }

#define MFMA_BODY(t) { \
  const char* sb_ = lds + ((t) & 3) * SLOT; \
  s8v bf_[4], af_[4]; \
  _Pragma("unroll") \
  for (int ni_ = 0; ni_ < 4; ni_++) bf_[ni_] = *(const s8v*)(sb_ + offB[ni_]); \
  _Pragma("unroll") \
  for (int mi_ = 0; mi_ < 4; mi_++) af_[mi_] = *(const s8v*)(sb_ + offA[mi_]); \
  __builtin_amdgcn_s_setprio(1); \
  _Pragma("unroll") \
  for (int mi_ = 0; mi_ < 4; mi_++) \
    _Pragma("unroll") \
    for (int ni_ = 0; ni_ < 4; ni_++) \
      acc[mi_][ni_] = __builtin_amdgcn_mfma_f32_16x16x32_bf16( \
          af_[mi_], bf_[ni_], acc[mi_][ni_], 0, 0, 0); \
  __builtin_amdgcn_s_setprio(0); \
  _Pragma("unroll") \
  for (int mi_ = 0; mi_ < 4; mi_++) af_[mi_] = *(const s8v*)(sb_ + offA[4 + mi_]); \
  __builtin_amdgcn_s_setprio(1); \
  _Pragma("unroll") \
  for (int mi_ = 0; mi_ < 4; mi_++) \
    _Pragma("unroll") \
    for (int ni_ = 0; ni_ < 4; ni_++) \
      acc[4 + mi_][ni_] = __builtin_amdgcn_mfma_f32_16x16x32_bf16( \
          af_[mi_], bf_[ni_], acc[4 + mi_][ni_], 0, 0, 0); \
  __builtin_amdgcn_s_setprio(0); }

#define ENDBAR() { \
  asm volatile("s_waitcnt lgkmcnt(0)" ::: "memory"); \
  __builtin_amdgcn_s_barrier(); }

  // prologue (R13-proven single-set pattern): tile 0 staged; tile 1 loads
  // in flight; slot 0 published block-wide.
  ISSUE(0);
  CVTWRITE(0);              // compiler inserts vmcnt waits via reg deps
  ISSUE(1);
  ENDBAR();

  // invariant at iter t: slot t&3 ready; staging set holds tile t+1's f32
  // (issued one full iteration earlier ~1500cyc > 900cyc HBM latency).
  // Slot (t+1)&3 written at t, last read at t-3: 4-barrier reuse distance.
  for (int t = 0; t < NT; ++t) {
    MFMA_BODY(t);
    if (t + 1 < NT) {
      CVTWRITE(t + 1);                  // consumes set (tile t+1)
      if (t + 2 < NT) ISSUE(t + 2);     // refill set
      ENDBAR();
    }
  }

  // epilogue: C/D frag layout col=lane&15, row=(lane>>4)*4+r  [m89]
  const long cB = (long)batch * J.sCb;
#pragma unroll
  for (int mi = 0; mi < 8; mi++) {
    const int rbase = brow + wm * 128 + mi * 16 + fq * 4;
#pragma unroll
    for (int ni = 0; ni < 4; ni++) {
      const int col = bcol + wn * 64 + ni * 16 + fr;
      const float bc = (J.bmode == 1) ? J.bias[col] : 0.f;
#pragma unroll
      for (int r = 0; r < 4; r++) {
        const int row = rbase + r;
        float v = acc[mi][ni][r] + ((J.bmode == 2) ? J.bias[row] : bc);
        J.C[cB + (long)row * J.ldc + col] = f2b(v);
      }
    }
  }
#undef ISSUE
#undef CVTWRITE
#undef MFMA_BODY
#undef ENDBAR
}

// ---------------- gemmJ: bf16-source GEMM (scores / PV), R8-proven -------
struct Job {
  const unsigned short* A; const unsigned short* B; void* C;
  const float* bias; const float* mask; float* sRow;
  long sAb, sBb, sCb, sMb;
  int lda, ldb, ldc, ldM;
  int K, tilesN, tilesMN;
  float scale; int bmode;
};

// MODE 1: exp(.*scale+mask) -> bf16 out + atomic row sums (scores).
// MODE 2: f32 out * (1/sRow[row]) (PV with normalization).
template <int NFRAG, int MODE>
__global__ __launch_bounds__(512, 2) void gemmJ(Job j0, Job j1, Job j2,
                                                int b0, int b1) {
  constexpr int BN = NFRAG * 64;
  constexpr int ASLOT = 256 * 64;
  constexpr int BSLOT = BN * 64;
  constexpr int SLOT = ASLOT + BSLOT;
  constexpr int CH = SLOT / 1024;
  constexpr int GPW = CH / 8;
  static_assert(4 * SLOT <= 160 * 1024, "LDS budget");
  __shared__ __align__(16) char lds[4 * SLOT];   // ring-4: 2-barrier reuse

  const int nwg = gridDim.x;
  const int hw = blockIdx.x;
  int g = (hw & 7) * (nwg >> 3) + (hw >> 3);
  const Job J = (g < b0) ? j0 : (g < b1) ? j1 : j2;
  g -= (g < b0) ? 0 : (g < b1) ? b0 : b1;

  const int batch = g / J.tilesMN;
  const int tt = g - batch * J.tilesMN;
  const int tm = tt / J.tilesN, tn = tt - tm * J.tilesN;
  const int brow = tm << 8, bcol = tn * BN;

  const int tid = threadIdx.x;
  const int lane = tid & 63, w = tid >> 6;
  const int wm = w >> 2, wn = w & 3;
  const int fr = lane & 15, fq = lane >> 4;

  const unsigned short* Ab = J.A + (long)batch * J.sAb;
  const unsigned short* Bb = J.B + (long)batch * J.sBb;

  const unsigned short* gsrc[GPW];
  int ldsdst[GPW];
#pragma unroll
  for (int i = 0; i < GPW; i++) {
    const int c = w + i * 8;
    const bool isA = (c < 16);
    const int cc = isA ? c : c - 16;
    const int roff = cc * 1024 + lane * 16;
    const int L = roff ^ (((roff >> 7) & 7) << 4);
    const int row = L >> 6, colb = L & 63;
    gsrc[i] = (isA ? (Ab + (long)(brow + row) * J.lda)
                   : (Bb + (long)(bcol + row) * J.ldb)) + (colb >> 1);
    ldsdst[i] = (isA ? 0 : ASLOT) + cc * 1024;
  }

  int offA[8], offB[NFRAG];
#pragma unroll
  for (int mi = 0; mi < 8; mi++) {
    const int oa = (wm * 128 + mi * 16 + fr) * 64 + fq * 16;
    offA[mi] = oa ^ (((oa >> 7) & 7) << 4);
  }
#pragma unroll
  for (int ni = 0; ni < NFRAG; ni++) {
    const int ob = (wn * (NFRAG * 16) + ni * 16 + fr) * 64 + fq * 16;
    offB[ni] = ASLOT + (ob ^ (((ob >> 7) & 7) << 4));
  }

  f32x4 acc[8][NFRAG];
#pragma unroll
  for (int mi = 0; mi < 8; mi++)
#pragma unroll
    for (int ni = 0; ni < NFRAG; ni++) acc[mi][ni] = (f32x4){0.f, 0.f, 0.f, 0.f};

  const int NT = J.K >> 5;

#define STAGE(kt) { \
  char* const sb_ = lds + ((kt) & 3) * SLOT; \
  _Pragma("unroll") \
  for (int i_ = 0; i_ < GPW; i_++) \
    gload_lds16(gsrc[i_] + (long)(kt) * 32, sb_ + ldsdst[i_]); }

  STAGE(0);
  STAGE(1);
  waitvm<GPW>();
  __builtin_amdgcn_s_barrier();

  for (int t = 0; t < NT; ++t) {
    const char* sb = lds + (t & 3) * SLOT;
    if (t + 2 < NT) STAGE(t + 2);

    s8v bf[NFRAG], af[4];
#pragma unroll
    for (int ni = 0; ni < NFRAG; ni++) bf[ni] = *(const s8v*)(sb + offB[ni]);
#pragma unroll
    for (int mi = 0; mi < 4; mi++) af[mi] = *(const s8v*)(sb + offA[mi]);
    __builtin_amdgcn_s_setprio(1);
#pragma unroll
    for (int mi = 0; mi < 4; mi++)
#pragma unroll
      for (int ni = 0; ni < NFRAG; ni++)
        acc[mi][ni] = __builtin_amdgcn_mfma_f32_16x16x32_bf16(
            af[mi], bf[ni], acc[mi][ni], 0, 0, 0);
    __builtin_amdgcn_s_setprio(0);
#pragma unroll
    for (int mi = 0; mi < 4; mi++) af[mi] = *(const s8v*)(sb + offA[4 + mi]);
    __builtin_amdgcn_s_setprio(1);
#pragma unroll
    for (int mi = 0; mi < 4; mi++)
#pragma unroll
      for (int ni = 0; ni < NFRAG; ni++)
        acc[4 + mi][ni] = __builtin_amdgcn_mfma_f32_16x16x32_bf16(
            af[mi], bf[ni], acc[4 + mi][ni], 0, 0, 0);
    __builtin_amdgcn_s_setprio(0);

    if (t + 1 < NT) {
      if (t + 2 < NT) waitvm<GPW>();
      else            waitvm<0>();
      __builtin_amdgcn_s_barrier();
    }
  }

  unsigned short* Cb = (unsigned short*)J.C;
  float* Cf = (float*)J.C;
  const long cB = (long)batch * J.sCb;
  const float* maskB = (MODE == 1) ? (J.mask + (long)batch * J.sMb) : nullptr;
  float* sB = (J.sRow != nullptr) ? (J.sRow + batch * 2048) : nullptr;

#pragma unroll
  for (int mi = 0; mi < 8; mi++) {
    const int rbase = brow + wm * 128 + mi * 16 + fq * 4;

    if constexpr (MODE == 1) {
      float rs[4] = {0.f, 0.f, 0.f, 0.f};
#pragma unroll
      for (int ni = 0; ni < NFRAG; ni++) {
        const int col = bcol + wn * (NFRAG * 16) + ni * 16 + fr;
#pragma unroll
        for (int r = 0; r < 4; r++) {
          const int row = rbase + r;
          float v = acc[mi][ni][r] * J.scale + maskB[(long)row * J.ldM + col];
          v = __expf(v);
          Cb[cB + (long)row * J.ldc + col] = f2b(v);
          rs[r] += v;
        }
      }
#pragma unroll
      for (int off = 1; off < 16; off <<= 1) {
#pragma unroll
        for (int r = 0; r < 4; r++) rs[r] += __shfl_xor(rs[r], off, 64);
      }
      if (fr == 0) {
#pragma unroll
        for (int r = 0; r < 4; r++) atomicAdd(&sB[rbase + r], rs[r]);
      }
    } else {  // MODE 2: PV, normalize by 1/sRow
      float inv[4];
#pragma unroll
      for (int r = 0; r < 4; r++) inv[r] = 1.0f / sB[rbase + r];
#pragma unroll
      for (int ni = 0; ni < NFRAG; ni++) {
        const int col = bcol + wn * (NFRAG * 16) + ni * 16 + fr;
#pragma unroll
        for (int r = 0; r < 4; r++) {
          const int row = rbase + r;
          Cf[cB + (long)row * J.ldc + col] = acc[mi][ni][r] * inv[r];
        }
      }
    }
  }
#undef STAGE
}

// zero sRow[8192]
__global__ __launch_bounds__(256) void zeroS(float* sz) {
  sz[blockIdx.x * 256 + threadIdx.x] = 0.f;
}

extern "C" void kernel_launch(void* const* d_in, const int* in_sizes, int n_in,
                              void* d_out, int out_size, void* d_ws, size_t ws_size,
                              hipStream_t stream) {
  const float* q    = (const float*)d_in[0];
  const float* k    = (const float*)d_in[1];
  const float* v    = (const float*)d_in[2];
  const float* mask = (const float*)d_in[3];
  const float* Wq   = (const float*)d_in[4];
  const float* bq   = (const float*)d_in[5];
  const float* Wk   = (const float*)d_in[6];
  const float* bk   = (const float*)d_in[7];
  const float* Wv   = (const float*)d_in[8];
  const float* bv   = (const float*)d_in[9];
  float* out = (float*)d_out;

  const size_t MB = 1ull << 20;
  if (ws_size < 134 * MB) return;
  char* ws = (char*)d_ws;
  unsigned short* qb  = (unsigned short*)(ws + 0 * MB);
  unsigned short* kb  = (unsigned short*)(ws + 16 * MB);
  unsigned short* vT  = (unsigned short*)(ws + 32 * MB);
  float*          sRw = (float*)(ws + 48 * MB);           // 32KB
  unsigned short* Sb  = (unsigned short*)(ws + 80 * MB);  // 32MB

  zeroS<<<32, 256, 0, stream>>>(sRw);

  // QKV fused from raw f32, 256x256 tiles (384 blocks):
  // q-proj 128 (32 tm x 4 tn), k-proj 128, v-proj 128 (4 tm x 8 tn x 4 b).
  JobF fq = { q, Wq, qb, bq, 0, 0, 0, 1024, 1024, 1024, 4, 128, 1 };
  JobF fk = { k, Wk, kb, bk, 0, 0, 0, 1024, 1024, 1024, 4, 128, 1 };
  JobF fv = { Wv, v, vT, bv, 0, 2048L * 1024, 1024L * 2048,
              1024, 1024, 2048, 8, 32, 2 };
  gemmF<<<384, 512, 0, stream>>>(fq, fk, fv, 128, 256);

  // scores -> E = exp(qk/32 + mask), bf16, + row sums. 8x8x4 = 256 blocks.
  Job js = { qb, kb, (void*)Sb, nullptr, mask, sRw,
             2048L * 1024, 2048L * 1024, 2048L * 2048, 2048L * 2048,
             1024, 1024, 2048, 2048, 1024, 8, 64, 0.03125f, 0 };
  gemmJ<4, 1><<<256, 512, 0, stream>>>(js, js, js, 256, 256);

  // PV: out = (E . vT^T) / sRow; 8 tm x 8 tn x 4 = 256 blocks, K=2048.
  Job jp = { Sb, vT, (void*)out, nullptr, nullptr, sRw,
             2048L * 2048, 1024L * 2048, 2048L * 1024, 0,
             2048, 2048, 1024, 0, 2048, 8, 64, 1.0f, 0 };
  gemmJ<2, 2><<<256, 512, 0, stream>>>(jp, jp, jp, 256, 256);
}

// Round 19
// 216.081 us; speedup vs baseline: 1.0800x; 1.0159x over previous
//
#include <hip/hip_runtime.h>
#include <stdint.h>

// Fused attention: q/k/v projections + softmax(QK^T/32 + mask) @ V
// B=4, S=2048, E=1024.
// R19 = R18 schedule + sRow-zeroing fix (R18 re-validation failure: cvtW
// zeroed only 2048/8192 sRow entries -> batches 1-3 accumulated across
// graph replays; grid-stride loop now covers all 8192 — cvt7-proven).
// Schedule:
//   L0 cvtW: v,Wv -> bf16 + zero sRow[8192] (904 blocks)
//   L1 gemmF: q-proj + k-proj from raw f32 (256 blocks = 1 full gen)
//   L2 gemmJ<4,1>: scores (256) + v-proj (128) packed, epilogue branches
//      per-block on bmode (0 = exp+rowsum, else bias-store bf16)
//   L3 gemmJ<2,2>: PV (256)
// gemmF = R17 proven; gemmJ = R8 proven ring-4 BK=32 gload_lds structure.
// Softmax eliminated: E=exp(x/32+mask) bounded ~e^6; PV scales by 1/sRow.
//
// ws layout (MB offsets): [0,16) qb / [16,32) kb / [32,48) vT /
// [48,+32KB) sRow / [80,112) Sb=E / [112,128) xv / [132,134) Wvb.

typedef __attribute__((ext_vector_type(8))) short s8v;
typedef __attribute__((ext_vector_type(4))) float f32x4;
typedef __attribute__((ext_vector_type(4))) unsigned u32x4;

__device__ __forceinline__ unsigned short f2b(float f) {
  union { float f; unsigned u; } c; c.f = f;
  unsigned r = c.u + 0x7fffu + ((c.u >> 16) & 1u);   // RNE, no NaN inputs
  return (unsigned short)(r >> 16);
}

__device__ __forceinline__ void gload_lds16(const void* gsrc, void* ldst) {
  __builtin_amdgcn_global_load_lds(
      (__attribute__((address_space(1))) unsigned int*)(uintptr_t)gsrc,
      (__attribute__((address_space(3))) unsigned int*)(unsigned)(uintptr_t)ldst,
      16, 0, 0);
}

template <int N> __device__ __forceinline__ void waitvm() {
  if constexpr (N == 4)      asm volatile("s_waitcnt vmcnt(4)" ::: "memory");
  else if constexpr (N == 3) asm volatile("s_waitcnt vmcnt(3)" ::: "memory");
  else                       asm volatile("s_waitcnt vmcnt(0)" ::: "memory");
}

// ---------------- gemmF: q/k projection from f32 sources (R17) ----------
struct JobF {
  const float* A; const float* B; unsigned short* C; const float* bias;
  long sAb, sBb, sCb;
  int lda, ldb, ldc, tilesN, tilesMN, bmode;   // bias: 1=col, 2=row
};

// NT GEMM from f32: C[m][n] = bf16(sum_k A[m][k]B[n][k] + bias). 256x256
// tile, 8 waves (2Mx4N, per-wave 128x64), BK=32, K=1024 fixed (NT=32),
// ring-4 LDS, single-set reg staging + v_cvt_pk_bf16_f32 + ds_write.
__global__ __launch_bounds__(512, 1) void gemmF(JobF j0, JobF j1, JobF j2,
                                                int b0, int b1) {
  constexpr int ASLOT = 256 * 64;
  constexpr int SLOT = 2 * ASLOT;
  constexpr int NT = 32;
  __shared__ __align__(16) char lds[4 * SLOT];   // 128KB

  const int nwg = gridDim.x;
  const int hw = blockIdx.x;
  int g = (hw & 7) * (nwg >> 3) + (hw >> 3);
  const JobF J = (g < b0) ? j0 : (g < b1) ? j1 : j2;
  g -= (g < b0) ? 0 : (g < b1) ? b0 : b1;

  const int batch = g / J.tilesMN;
  const int tt = g - batch * J.tilesMN;
  const int tm = tt / J.tilesN, tn = tt - tm * J.tilesN;
  const int brow = tm << 8, bcol = tn << 8;

  const int tid = threadIdx.x, lane = tid & 63, w = tid >> 6;
  const int wm = w >> 2, wn = w & 3;
  const int fr = lane & 15, fq = lane >> 4;

  const float* Ab = J.A + (long)batch * J.sAb;
  const float* Bb = J.B + (long)batch * J.sBb;

  const float* gsrcF[4];
  int ldsdst[4];
#pragma unroll
  for (int i = 0; i < 4; i++) {
    const int c = w + i * 8;
    const bool isA = (c < 16);
    const int cc = isA ? c : c - 16;
    const int roff = cc * 1024 + lane * 16;
    const int L = roff ^ (((roff >> 7) & 7) << 4);
    const int row = L >> 6, elem = (L & 63) >> 1;
    gsrcF[i] = (isA ? (Ab + (long)(brow + row) * J.lda)
                    : (Bb + (long)(bcol + row) * J.ldb)) + elem;
    ldsdst[i] = (isA ? 0 : ASLOT) + cc * 1024 + lane * 16;
  }

  int offA[8], offB[4];
#pragma unroll
  for (int mi = 0; mi < 8; mi++) {
    const int oa = (wm * 128 + mi * 16 + fr) * 64 + fq * 16;
    offA[mi] = oa ^ (((oa >> 7) & 7) << 4);
  }
#pragma unroll
  for (int ni = 0; ni < 4; ni++) {
    const int ob = (wn * 64 + ni * 16 + fr) * 64 + fq * 16;
    offB[ni] = ASLOT + (ob ^ (((ob >> 7) & 7) << 4));
  }

  f32x4 acc[8][4];
#pragma unroll
  for (int mi = 0; mi < 8; mi++)
#pragma unroll
    for (int ni = 0; ni < 4; ni++) acc[mi][ni] = (f32x4){0.f, 0.f, 0.f, 0.f};

  f32x4 sLo[4], sHi[4];

#define ISSUE(kt) { \
  _Pragma("unroll") \
  for (int i_ = 0; i_ < 4; i_++) { \
    const float* p_ = gsrcF[i_] + (long)(kt) * 32; \
    sLo[i_] = *(const f32x4*)p_; sHi[i_] = *(const f32x4*)(p_ + 4); } }

#define CVTWRITE(kt) { \
  char* const sb_ = lds + ((kt) & 3) * SLOT; \
  _Pragma("unroll") \
  for (int i_ = 0; i_ < 4; i_++) { \
    unsigned o0_, o1_, o2_, o3_; \
    asm("v_cvt_pk_bf16_f32 %0, %1, %2" : "=v"(o0_) : "v"(sLo[i_][0]), "v"(sLo[i_][1])); \
    asm("v_cvt_pk_bf16_f32 %0, %1, %2" : "=v"(o1_) : "v"(sLo[i_][2]), "v"(sLo[i_][3])); \
    asm("v_cvt_pk_bf16_f32 %0, %1, %2" : "=v"(o2_) : "v"(sHi[i_][0]), "v"(sHi[i_][1])); \
    asm("v_cvt_pk_bf16_f32 %0, %1, %2" : "=v"(o3_) : "v"(sHi[i_][2]), "v"(sHi[i_][3])); \
    *(u32x4*)(sb_ + ldsdst[i_]) = (u32x4){o0_, o1_, o2_, o3_}; } }

#define MFMA_BODY(t) { \
  const char* sb_ = lds + ((t) & 3) * SLOT; \
  s8v bf_[4], af_[4]; \
  _Pragma("unroll") \
  for (int ni_ = 0; ni_ < 4; ni_++) bf_[ni_] = *(const s8v*)(sb_ + offB[ni_]); \
  _Pragma("unroll") \
  for (int mi_ = 0; mi_ < 4; mi_++) af_[mi_] = *(const s8v*)(sb_ + offA[mi_]); \
  __builtin_amdgcn_s_setprio(1); \
  _Pragma("unroll") \
  for (int mi_ = 0; mi_ < 4; mi_++) \
    _Pragma("unroll") \
    for (int ni_ = 0; ni_ < 4; ni_++) \
      acc[mi_][ni_] = __builtin_amdgcn_mfma_f32_16x16x32_bf16( \
          af_[mi_], bf_[ni_], acc[mi_][ni_], 0, 0, 0); \
  __builtin_amdgcn_s_setprio(0); \
  _Pragma("unroll") \
  for (int mi_ = 0; mi_ < 4; mi_++) af_[mi_] = *(const s8v*)(sb_ + offA[4 + mi_]); \
  __builtin_amdgcn_s_setprio(1); \
  _Pragma("unroll") \
  for (int mi_ = 0; mi_ < 4; mi_++) \
    _Pragma("unroll") \
    for (int ni_ = 0; ni_ < 4; ni_++) \
      acc[4 + mi_][ni_] = __builtin_amdgcn_mfma_f32_16x16x32_bf16( \
          af_[mi_], bf_[ni_], acc[4 + mi_][ni_], 0, 0, 0); \
  __builtin_amdgcn_s_setprio(0); }

#define ENDBAR() { \
  asm volatile("s_waitcnt lgkmcnt(0)" ::: "memory"); \
  __builtin_amdgcn_s_barrier(); }

  ISSUE(0);
  CVTWRITE(0);
  ISSUE(1);
  ENDBAR();

  for (int t = 0; t < NT; ++t) {
    MFMA_BODY(t);
    if (t + 1 < NT) {
      CVTWRITE(t + 1);
      if (t + 2 < NT) ISSUE(t + 2);
      ENDBAR();
    }
  }

  const long cB = (long)batch * J.sCb;
#pragma unroll
  for (int mi = 0; mi < 8; mi++) {
    const int rbase = brow + wm * 128 + mi * 16 + fq * 4;
#pragma unroll
    for (int ni = 0; ni < 4; ni++) {
      const int col = bcol + wn * 64 + ni * 16 + fr;
      const float bc = (J.bmode == 1) ? J.bias[col] : 0.f;
#pragma unroll
      for (int r = 0; r < 4; r++) {
        const int row = rbase + r;
        float v = acc[mi][ni][r] + ((J.bmode == 2) ? J.bias[row] : bc);
        J.C[cB + (long)row * J.ldc + col] = f2b(v);
      }
    }
  }
#undef ISSUE
#undef CVTWRITE
#undef MFMA_BODY
#undef ENDBAR
}

// ---------------- gemmJ: bf16-source GEMM (scores+vproj / PV) -----------
struct Job {
  const unsigned short* A; const unsigned short* B; void* C;
  const float* bias; const float* mask; float* sRow;
  long sAb, sBb, sCb, sMb;
  int lda, ldb, ldc, ldM;
  int K, tilesN, tilesMN;
  float scale; int bmode;   // MODE1: 0 = exp+rowsum; 1/2 = bias col/row
};

// MODE 1: bmode==0 -> exp(.*scale+mask), bf16 out + atomic row sums;
//         bmode!=0 -> bias-add, bf16 out (v-projection packed in).
// MODE 2: f32 out * (1/sRow[row]) (PV with normalization).
template <int NFRAG, int MODE>
__global__ __launch_bounds__(512, 2) void gemmJ(Job j0, Job j1, Job j2,
                                                int b0, int b1) {
  constexpr int BN = NFRAG * 64;
  constexpr int ASLOT = 256 * 64;
  constexpr int BSLOT = BN * 64;
  constexpr int SLOT = ASLOT + BSLOT;
  constexpr int CH = SLOT / 1024;
  constexpr int GPW = CH / 8;
  static_assert(4 * SLOT <= 160 * 1024, "LDS budget");
  __shared__ __align__(16) char lds[4 * SLOT];   // ring-4: 2-barrier reuse

  const int nwg = gridDim.x;
  const int hw = blockIdx.x;
  int g = (hw & 7) * (nwg >> 3) + (hw >> 3);
  const Job J = (g < b0) ? j0 : (g < b1) ? j1 : j2;
  g -= (g < b0) ? 0 : (g < b1) ? b0 : b1;

  const int batch = g / J.tilesMN;
  const int tt = g - batch * J.tilesMN;
  const int tm = tt / J.tilesN, tn = tt - tm * J.tilesN;
  const int brow = tm << 8, bcol = tn * BN;

  const int tid = threadIdx.x;
  const int lane = tid & 63, w = tid >> 6;
  const int wm = w >> 2, wn = w & 3;
  const int fr = lane & 15, fq = lane >> 4;

  const unsigned short* Ab = J.A + (long)batch * J.sAb;
  const unsigned short* Bb = J.B + (long)batch * J.sBb;

  const unsigned short* gsrc[GPW];
  int ldsdst[GPW];
#pragma unroll
  for (int i = 0; i < GPW; i++) {
    const int c = w + i * 8;
    const bool isA = (c < 16);
    const int cc = isA ? c : c - 16;
    const int roff = cc * 1024 + lane * 16;
    const int L = roff ^ (((roff >> 7) & 7) << 4);
    const int row = L >> 6, colb = L & 63;
    gsrc[i] = (isA ? (Ab + (long)(brow + row) * J.lda)
                   : (Bb + (long)(bcol + row) * J.ldb)) + (colb >> 1);
    ldsdst[i] = (isA ? 0 : ASLOT) + cc * 1024;
  }

  int offA[8], offB[NFRAG];
#pragma unroll
  for (int mi = 0; mi < 8; mi++) {
    const int oa = (wm * 128 + mi * 16 + fr) * 64 + fq * 16;
    offA[mi] = oa ^ (((oa >> 7) & 7) << 4);
  }
#pragma unroll
  for (int ni = 0; ni < NFRAG; ni++) {
    const int ob = (wn * (NFRAG * 16) + ni * 16 + fr) * 64 + fq * 16;
    offB[ni] = ASLOT + (ob ^ (((ob >> 7) & 7) << 4));
  }

  f32x4 acc[8][NFRAG];
#pragma unroll
  for (int mi = 0; mi < 8; mi++)
#pragma unroll
    for (int ni = 0; ni < NFRAG; ni++) acc[mi][ni] = (f32x4){0.f, 0.f, 0.f, 0.f};

  const int NT = J.K >> 5;

#define STAGE(kt) { \
  char* const sb_ = lds + ((kt) & 3) * SLOT; \
  _Pragma("unroll") \
  for (int i_ = 0; i_ < GPW; i_++) \
    gload_lds16(gsrc[i_] + (long)(kt) * 32, sb_ + ldsdst[i_]); }

  STAGE(0);
  STAGE(1);
  waitvm<GPW>();
  __builtin_amdgcn_s_barrier();

  for (int t = 0; t < NT; ++t) {
    const char* sb = lds + (t & 3) * SLOT;
    if (t + 2 < NT) STAGE(t + 2);

    s8v bf[NFRAG], af[4];
#pragma unroll
    for (int ni = 0; ni < NFRAG; ni++) bf[ni] = *(const s8v*)(sb + offB[ni]);
#pragma unroll
    for (int mi = 0; mi < 4; mi++) af[mi] = *(const s8v*)(sb + offA[mi]);
    __builtin_amdgcn_s_setprio(1);
#pragma unroll
    for (int mi = 0; mi < 4; mi++)
#pragma unroll
      for (int ni = 0; ni < NFRAG; ni++)
        acc[mi][ni] = __builtin_amdgcn_mfma_f32_16x16x32_bf16(
            af[mi], bf[ni], acc[mi][ni], 0, 0, 0);
    __builtin_amdgcn_s_setprio(0);
#pragma unroll
    for (int mi = 0; mi < 4; mi++) af[mi] = *(const s8v*)(sb + offA[4 + mi]);
    __builtin_amdgcn_s_setprio(1);
#pragma unroll
    for (int mi = 0; mi < 4; mi++)
#pragma unroll
      for (int ni = 0; ni < NFRAG; ni++)
        acc[4 + mi][ni] = __builtin_amdgcn_mfma_f32_16x16x32_bf16(
            af[mi], bf[ni], acc[4 + mi][ni], 0, 0, 0);
    __builtin_amdgcn_s_setprio(0);

    if (t + 1 < NT) {
      if (t + 2 < NT) waitvm<GPW>();
      else            waitvm<0>();
      __builtin_amdgcn_s_barrier();
    }
  }

  unsigned short* Cb = (unsigned short*)J.C;
  float* Cf = (float*)J.C;
  const long cB = (long)batch * J.sCb;
  const float* maskB = (MODE == 1) ? (J.mask + (long)batch * J.sMb) : nullptr;
  float* sB = J.sRow + batch * 2048;

#pragma unroll
  for (int mi = 0; mi < 8; mi++) {
    const int rbase = brow + wm * 128 + mi * 16 + fq * 4;

    if constexpr (MODE == 1) {
      if (J.bmode != 0) {       // packed v-projection: bias-add, bf16 out
#pragma unroll
        for (int ni = 0; ni < NFRAG; ni++) {
          const int col = bcol + wn * (NFRAG * 16) + ni * 16 + fr;
          const float bc = (J.bmode == 1) ? J.bias[col] : 0.f;
#pragma unroll
          for (int r = 0; r < 4; r++) {
            const int row = rbase + r;
            float v = acc[mi][ni][r] + ((J.bmode == 2) ? J.bias[row] : bc);
            Cb[cB + (long)row * J.ldc + col] = f2b(v);
          }
        }
      } else {                  // scores: exp + row sums
        float rs[4] = {0.f, 0.f, 0.f, 0.f};
#pragma unroll
        for (int ni = 0; ni < NFRAG; ni++) {
          const int col = bcol + wn * (NFRAG * 16) + ni * 16 + fr;
#pragma unroll
          for (int r = 0; r < 4; r++) {
            const int row = rbase + r;
            float v = acc[mi][ni][r] * J.scale + maskB[(long)row * J.ldM + col];
            v = __expf(v);
            Cb[cB + (long)row * J.ldc + col] = f2b(v);
            rs[r] += v;
          }
        }
#pragma unroll
        for (int off = 1; off < 16; off <<= 1) {
#pragma unroll
          for (int r = 0; r < 4; r++) rs[r] += __shfl_xor(rs[r], off, 64);
        }
        if (fr == 0) {
#pragma unroll
          for (int r = 0; r < 4; r++) atomicAdd(&sB[rbase + r], rs[r]);
        }
      }
    } else {  // MODE 2: PV, normalize by 1/sRow
      float inv[4];
#pragma unroll
      for (int r = 0; r < 4; r++) inv[r] = 1.0f / sB[rbase + r];
#pragma unroll
      for (int ni = 0; ni < NFRAG; ni++) {
        const int col = bcol + wn * (NFRAG * 16) + ni * 16 + fr;
#pragma unroll
        for (int r = 0; r < 4; r++) {
          const int row = rbase + r;
          Cf[cB + (long)row * J.ldc + col] = acc[mi][ni][r] * inv[r];
        }
      }
    }
  }
#undef STAGE
}

// cvt v (768 blocks) + Wv (128 blocks) -> bf16; zero sRow[8192] (8 blocks,
// grid-stride — R18 bug: single-store only covered 2048 entries, batches
// 1-3 accumulated across graph replays).
__global__ __launch_bounds__(256) void cvtW(
    const float* v, unsigned short* xv,
    const float* Wv, unsigned short* Wvb, float* sz) {
  int bid = blockIdx.x;
  if (bid >= 896) {
    for (int i = (bid - 896) * 256 + threadIdx.x; i < 8192; i += 2048)
      sz[i] = 0.f;
    return;
  }
  const float* src; unsigned short* dst; long n8; int lb, nb;
  if (bid < 768) { src = v;  dst = xv;  n8 = 1048576; lb = bid;       nb = 768; }
  else           { src = Wv; dst = Wvb; n8 = 131072;  lb = bid - 768; nb = 128; }
  const long stride = (long)nb * 256;
  for (long i = (long)lb * 256 + threadIdx.x; i < n8; i += stride) {
    const float* p = src + i * 8;
    f32x4 va = *(const f32x4*)p;
    f32x4 vb = *(const f32x4*)(p + 4);
    s8v o;
    o[0] = (short)f2b(va[0]); o[1] = (short)f2b(va[1]);
    o[2] = (short)f2b(va[2]); o[3] = (short)f2b(va[3]);
    o[4] = (short)f2b(vb[0]); o[5] = (short)f2b(vb[1]);
    o[6] = (short)f2b(vb[2]); o[7] = (short)f2b(vb[3]);
    *(s8v*)(dst + i * 8) = o;
  }
}

extern "C" void kernel_launch(void* const* d_in, const int* in_sizes, int n_in,
                              void* d_out, int out_size, void* d_ws, size_t ws_size,
                              hipStream_t stream) {
  const float* q    = (const float*)d_in[0];
  const float* k    = (const float*)d_in[1];
  const float* v    = (const float*)d_in[2];
  const float* mask = (const float*)d_in[3];
  const float* Wq   = (const float*)d_in[4];
  const float* bq   = (const float*)d_in[5];
  const float* Wk   = (const float*)d_in[6];
  const float* bk   = (const float*)d_in[7];
  const float* Wv   = (const float*)d_in[8];
  const float* bv   = (const float*)d_in[9];
  float* out = (float*)d_out;

  const size_t MB = 1ull << 20;
  if (ws_size < 134 * MB) return;
  char* ws = (char*)d_ws;
  unsigned short* qb  = (unsigned short*)(ws + 0 * MB);
  unsigned short* kb  = (unsigned short*)(ws + 16 * MB);
  unsigned short* vT  = (unsigned short*)(ws + 32 * MB);
  float*          sRw = (float*)(ws + 48 * MB);           // 32KB
  unsigned short* Sb  = (unsigned short*)(ws + 80 * MB);  // 32MB
  unsigned short* xv  = (unsigned short*)(ws + 112 * MB);
  unsigned short* Wvb = (unsigned short*)(ws + 132 * MB);

  // L0: convert v + Wv to bf16, zero sRow[8192]
  cvtW<<<904, 256, 0, stream>>>(v, xv, Wv, Wvb, sRw);

  // L1: q,k projections from raw f32 — 256 blocks = exactly 1 generation.
  JobF fq = { q, Wq, qb, bq, 0, 0, 0, 1024, 1024, 1024, 4, 128, 1 };
  JobF fk = { k, Wk, kb, bk, 0, 0, 0, 1024, 1024, 1024, 4, 128, 1 };
  gemmF<<<256, 512, 0, stream>>>(fq, fk, fk, 128, 256);

  // L2: scores (256 blocks, bmode=0 -> exp+rowsum) + v-proj (128 blocks,
  // bmode=2 -> bias, vT[f][s] = Wv.xv^T: 4 tm x 8 tn x 4 b). 384 blocks.
  Job js = { qb, kb, (void*)Sb, nullptr, mask, sRw,
             2048L * 1024, 2048L * 1024, 2048L * 2048, 2048L * 2048,
             1024, 1024, 2048, 2048, 1024, 8, 64, 0.03125f, 0 };
  Job jv = { Wvb, xv, (void*)vT, bv, nullptr, sRw,
             0, 2048L * 1024, 1024L * 2048, 0,
             1024, 1024, 2048, 0, 1024, 8, 32, 1.0f, 2 };
  gemmJ<4, 1><<<384, 512, 0, stream>>>(js, js, jv, 256, 256);

  // L3: PV: out = (E . vT^T) / sRow; 8 tm x 8 tn x 4 = 256 blocks, K=2048.
  Job jp = { Sb, vT, (void*)out, nullptr, nullptr, sRw,
             2048L * 2048, 1024L * 2048, 2048L * 1024, 0,
             2048, 2048, 1024, 0, 2048, 8, 64, 1.0f, 0 };
  gemmJ<2, 2><<<256, 512, 0, stream>>>(jp, jp, jp, 256, 256);
}

// Round 20
// 213.177 us; speedup vs baseline: 1.0947x; 1.0136x over previous
//
#include <hip/hip_runtime.h>
#include <stdint.h>

// Fused attention: q/k/v projections + softmax(QK^T/32 + mask) @ V
// B=4, S=2048, E=1024.
// R20 = R19 schedule with 16-wave (1024-thread) gemmJ16 for the N4 paths:
// same 256x256 tile / ring-4 / BK=32 / stage-2-ahead / vmcnt gate / swizzle,
// but wave grid 4Mx4N (per-wave 64x64, acc 64 VGPR) -> 4 waves/SIMD TLP
// without duplicating LDS panels (R16: extra BLOCKS null; intra-block waves
// untested until now). PV keeps proven 512-thread gemmJ<2,2>.
// Schedule: L0 cvtW (v,Wv->bf16 + zero sRow) / L1 gemmF qk-proj (256) /
// L2 gemmJ16 scores(256)+vproj(128) / L3 gemmJ<2,2> PV (256).
// Softmax eliminated: E=exp(x/32+mask) bounded ~e^6; PV scales by 1/sRow.
//
// ws layout (MB offsets): [0,16) qb / [16,32) kb / [32,48) vT /
// [48,+32KB) sRow / [80,112) Sb=E / [112,128) xv / [132,134) Wvb.

typedef __attribute__((ext_vector_type(8))) short s8v;
typedef __attribute__((ext_vector_type(4))) float f32x4;
typedef __attribute__((ext_vector_type(4))) unsigned u32x4;

__device__ __forceinline__ unsigned short f2b(float f) {
  union { float f; unsigned u; } c; c.f = f;
  unsigned r = c.u + 0x7fffu + ((c.u >> 16) & 1u);   // RNE, no NaN inputs
  return (unsigned short)(r >> 16);
}

__device__ __forceinline__ void gload_lds16(const void* gsrc, void* ldst) {
  __builtin_amdgcn_global_load_lds(
      (__attribute__((address_space(1))) unsigned int*)(uintptr_t)gsrc,
      (__attribute__((address_space(3))) unsigned int*)(unsigned)(uintptr_t)ldst,
      16, 0, 0);
}

template <int N> __device__ __forceinline__ void waitvm() {
  if constexpr (N == 4)      asm volatile("s_waitcnt vmcnt(4)" ::: "memory");
  else if constexpr (N == 3) asm volatile("s_waitcnt vmcnt(3)" ::: "memory");
  else if constexpr (N == 2) asm volatile("s_waitcnt vmcnt(2)" ::: "memory");
  else                       asm volatile("s_waitcnt vmcnt(0)" ::: "memory");
}

// ---------------- gemmF: q/k projection from f32 sources (R17) ----------
struct JobF {
  const float* A; const float* B; unsigned short* C; const float* bias;
  long sAb, sBb, sCb;
  int lda, ldb, ldc, tilesN, tilesMN, bmode;   // bias: 1=col, 2=row
};

__global__ __launch_bounds__(512, 1) void gemmF(JobF j0, JobF j1, JobF j2,
                                                int b0, int b1) {
  constexpr int ASLOT = 256 * 64;
  constexpr int SLOT = 2 * ASLOT;
  constexpr int NT = 32;
  __shared__ __align__(16) char lds[4 * SLOT];   // 128KB

  const int nwg = gridDim.x;
  const int hw = blockIdx.x;
  int g = (hw & 7) * (nwg >> 3) + (hw >> 3);
  const JobF J = (g < b0) ? j0 : (g < b1) ? j1 : j2;
  g -= (g < b0) ? 0 : (g < b1) ? b0 : b1;

  const int batch = g / J.tilesMN;
  const int tt = g - batch * J.tilesMN;
  const int tm = tt / J.tilesN, tn = tt - tm * J.tilesN;
  const int brow = tm << 8, bcol = tn << 8;

  const int tid = threadIdx.x, lane = tid & 63, w = tid >> 6;
  const int wm = w >> 2, wn = w & 3;
  const int fr = lane & 15, fq = lane >> 4;

  const float* Ab = J.A + (long)batch * J.sAb;
  const float* Bb = J.B + (long)batch * J.sBb;

  const float* gsrcF[4];
  int ldsdst[4];
#pragma unroll
  for (int i = 0; i < 4; i++) {
    const int c = w + i * 8;
    const bool isA = (c < 16);
    const int cc = isA ? c : c - 16;
    const int roff = cc * 1024 + lane * 16;
    const int L = roff ^ (((roff >> 7) & 7) << 4);
    const int row = L >> 6, elem = (L & 63) >> 1;
    gsrcF[i] = (isA ? (Ab + (long)(brow + row) * J.lda)
                    : (Bb + (long)(bcol + row) * J.ldb)) + elem;
    ldsdst[i] = (isA ? 0 : ASLOT) + cc * 1024 + lane * 16;
  }

  int offA[8], offB[4];
#pragma unroll
  for (int mi = 0; mi < 8; mi++) {
    const int oa = (wm * 128 + mi * 16 + fr) * 64 + fq * 16;
    offA[mi] = oa ^ (((oa >> 7) & 7) << 4);
  }
#pragma unroll
  for (int ni = 0; ni < 4; ni++) {
    const int ob = (wn * 64 + ni * 16 + fr) * 64 + fq * 16;
    offB[ni] = ASLOT + (ob ^ (((ob >> 7) & 7) << 4));
  }

  f32x4 acc[8][4];
#pragma unroll
  for (int mi = 0; mi < 8; mi++)
#pragma unroll
    for (int ni = 0; ni < 4; ni++) acc[mi][ni] = (f32x4){0.f, 0.f, 0.f, 0.f};

  f32x4 sLo[4], sHi[4];

#define ISSUE(kt) { \
  _Pragma("unroll") \
  for (int i_ = 0; i_ < 4; i_++) { \
    const float* p_ = gsrcF[i_] + (long)(kt) * 32; \
    sLo[i_] = *(const f32x4*)p_; sHi[i_] = *(const f32x4*)(p_ + 4); } }

#define CVTWRITE(kt) { \
  char* const sb_ = lds + ((kt) & 3) * SLOT; \
  _Pragma("unroll") \
  for (int i_ = 0; i_ < 4; i_++) { \
    unsigned o0_, o1_, o2_, o3_; \
    asm("v_cvt_pk_bf16_f32 %0, %1, %2" : "=v"(o0_) : "v"(sLo[i_][0]), "v"(sLo[i_][1])); \
    asm("v_cvt_pk_bf16_f32 %0, %1, %2" : "=v"(o1_) : "v"(sLo[i_][2]), "v"(sLo[i_][3])); \
    asm("v_cvt_pk_bf16_f32 %0, %1, %2" : "=v"(o2_) : "v"(sHi[i_][0]), "v"(sHi[i_][1])); \
    asm("v_cvt_pk_bf16_f32 %0, %1, %2" : "=v"(o3_) : "v"(sHi[i_][2]), "v"(sHi[i_][3])); \
    *(u32x4*)(sb_ + ldsdst[i_]) = (u32x4){o0_, o1_, o2_, o3_}; } }

#define MFMA_BODY(t) { \
  const char* sb_ = lds + ((t) & 3) * SLOT; \
  s8v bf_[4], af_[4]; \
  _Pragma("unroll") \
  for (int ni_ = 0; ni_ < 4; ni_++) bf_[ni_] = *(const s8v*)(sb_ + offB[ni_]); \
  _Pragma("unroll") \
  for (int mi_ = 0; mi_ < 4; mi_++) af_[mi_] = *(const s8v*)(sb_ + offA[mi_]); \
  __builtin_amdgcn_s_setprio(1); \
  _Pragma("unroll") \
  for (int mi_ = 0; mi_ < 4; mi_++) \
    _Pragma("unroll") \
    for (int ni_ = 0; ni_ < 4; ni_++) \
      acc[mi_][ni_] = __builtin_amdgcn_mfma_f32_16x16x32_bf16( \
          af_[mi_], bf_[ni_], acc[mi_][ni_], 0, 0, 0); \
  __builtin_amdgcn_s_setprio(0); \
  _Pragma("unroll") \
  for (int mi_ = 0; mi_ < 4; mi_++) af_[mi_] = *(const s8v*)(sb_ + offA[4 + mi_]); \
  __builtin_amdgcn_s_setprio(1); \
  _Pragma("unroll") \
  for (int mi_ = 0; mi_ < 4; mi_++) \
    _Pragma("unroll") \
    for (int ni_ = 0; ni_ < 4; ni_++) \
      acc[4 + mi_][ni_] = __builtin_amdgcn_mfma_f32_16x16x32_bf16( \
          af_[mi_], bf_[ni_], acc[4 + mi_][ni_], 0, 0, 0); \
  __builtin_amdgcn_s_setprio(0); }

#define ENDBAR() { \
  asm volatile("s_waitcnt lgkmcnt(0)" ::: "memory"); \
  __builtin_amdgcn_s_barrier(); }

  ISSUE(0);
  CVTWRITE(0);
  ISSUE(1);
  ENDBAR();

  for (int t = 0; t < NT; ++t) {
    MFMA_BODY(t);
    if (t + 1 < NT) {
      CVTWRITE(t + 1);
      if (t + 2 < NT) ISSUE(t + 2);
      ENDBAR();
    }
  }

  const long cB = (long)batch * J.sCb;
#pragma unroll
  for (int mi = 0; mi < 8; mi++) {
    const int rbase = brow + wm * 128 + mi * 16 + fq * 4;
#pragma unroll
    for (int ni = 0; ni < 4; ni++) {
      const int col = bcol + wn * 64 + ni * 16 + fr;
      const float bc = (J.bmode == 1) ? J.bias[col] : 0.f;
#pragma unroll
      for (int r = 0; r < 4; r++) {
        const int row = rbase + r;
        float v = acc[mi][ni][r] + ((J.bmode == 2) ? J.bias[row] : bc);
        J.C[cB + (long)row * J.ldc + col] = f2b(v);
      }
    }
  }
#undef ISSUE
#undef CVTWRITE
#undef MFMA_BODY
#undef ENDBAR
}

// ---------------- common Job ----------------
struct Job {
  const unsigned short* A; const unsigned short* B; void* C;
  const float* bias; const float* mask; float* sRow;
  long sAb, sBb, sCb, sMb;
  int lda, ldb, ldc, ldM;
  int K, tilesN, tilesMN;
  float scale; int bmode;   // 0 = exp+rowsum; 1/2 = bias col/row
};

// ------------- gemmJ16: 16-wave NFRAG=4 (scores + packed v-proj) --------
// 256x256 tile, 16 waves (4Mx4N, per-wave 64x64), BK=32, ring-4 LDS,
// stage-2-ahead gload_lds, vmcnt(2) gate, verified swizzle.
__global__ __launch_bounds__(1024, 1) void gemmJ16(Job j0, Job j1, Job j2,
                                                   int b0, int b1) {
  constexpr int ASLOT = 256 * 64;
  constexpr int SLOT = 2 * ASLOT;            // 32KB
  __shared__ __align__(16) char lds[4 * SLOT];   // 128KB

  const int nwg = gridDim.x;
  const int hw = blockIdx.x;
  int g = (hw & 7) * (nwg >> 3) + (hw >> 3);
  const Job J = (g < b0) ? j0 : (g < b1) ? j1 : j2;
  g -= (g < b0) ? 0 : (g < b1) ? b0 : b1;

  const int batch = g / J.tilesMN;
  const int tt = g - batch * J.tilesMN;
  const int tm = tt / J.tilesN, tn = tt - tm * J.tilesN;
  const int brow = tm << 8, bcol = tn << 8;

  const int tid = threadIdx.x;
  const int lane = tid & 63, w = tid >> 6;     // 16 waves: 4M x 4N
  const int wm = w >> 2, wn = w & 3;
  const int fr = lane & 15, fq = lane >> 4;

  const unsigned short* Ab = J.A + (long)batch * J.sAb;
  const unsigned short* Bb = J.B + (long)batch * J.sBb;

  // 32 1KB chunks/K-tile (A:0-15, B:16-31); wave w stages {w, w+16}.
  const unsigned short* gsrc[2];
  int ldsdst[2];
#pragma unroll
  for (int i = 0; i < 2; i++) {
    const int c = w + i * 16;
    const bool isA = (c < 16);
    const int cc = isA ? c : c - 16;
    const int roff = cc * 1024 + lane * 16;
    const int L = roff ^ (((roff >> 7) & 7) << 4);
    const int row = L >> 6, colb = L & 63;
    gsrc[i] = (isA ? (Ab + (long)(brow + row) * J.lda)
                   : (Bb + (long)(bcol + row) * J.ldb)) + (colb >> 1);
    ldsdst[i] = (isA ? 0 : ASLOT) + cc * 1024;
  }

  int offA[4], offB[4];
#pragma unroll
  for (int mi = 0; mi < 4; mi++) {
    const int oa = (wm * 64 + mi * 16 + fr) * 64 + fq * 16;
    offA[mi] = oa ^ (((oa >> 7) & 7) << 4);
  }
#pragma unroll
  for (int ni = 0; ni < 4; ni++) {
    const int ob = (wn * 64 + ni * 16 + fr) * 64 + fq * 16;
    offB[ni] = ASLOT + (ob ^ (((ob >> 7) & 7) << 4));
  }

  f32x4 acc[4][4];
#pragma unroll
  for (int mi = 0; mi < 4; mi++)
#pragma unroll
    for (int ni = 0; ni < 4; ni++) acc[mi][ni] = (f32x4){0.f, 0.f, 0.f, 0.f};

  const int NT = J.K >> 5;

#define STAGE16(kt) { \
  char* const sb_ = lds + ((kt) & 3) * SLOT; \
  gload_lds16(gsrc[0] + (long)(kt) * 32, sb_ + ldsdst[0]); \
  gload_lds16(gsrc[1] + (long)(kt) * 32, sb_ + ldsdst[1]); }

  STAGE16(0);
  STAGE16(1);
  waitvm<2>();
  __builtin_amdgcn_s_barrier();

  for (int t = 0; t < NT; ++t) {
    const char* sb = lds + (t & 3) * SLOT;
    if (t + 2 < NT) STAGE16(t + 2);          // slot (t+2)&3: 2-barrier reuse

    s8v bf[4], af[4];
#pragma unroll
    for (int ni = 0; ni < 4; ni++) bf[ni] = *(const s8v*)(sb + offB[ni]);
#pragma unroll
    for (int mi = 0; mi < 4; mi++) af[mi] = *(const s8v*)(sb + offA[mi]);
    __builtin_amdgcn_s_setprio(1);
#pragma unroll
    for (int mi = 0; mi < 4; mi++)
#pragma unroll
      for (int ni = 0; ni < 4; ni++)
        acc[mi][ni] = __builtin_amdgcn_mfma_f32_16x16x32_bf16(
            af[mi], bf[ni], acc[mi][ni], 0, 0, 0);
    __builtin_amdgcn_s_setprio(0);

    if (t + 1 < NT) {
      if (t + 2 < NT) waitvm<2>();           // tile t+1's 2 loads landed
      else            waitvm<0>();
      __builtin_amdgcn_s_barrier();
    }
  }

  // epilogue: C/D frag layout col=lane&15, row=(lane>>4)*4+r  [m89]
  unsigned short* Cb = (unsigned short*)J.C;
  const long cB = (long)batch * J.sCb;
  const float* maskB = J.mask + (long)batch * J.sMb;
  float* sB = J.sRow + batch * 2048;

#pragma unroll
  for (int mi = 0; mi < 4; mi++) {
    const int rbase = brow + wm * 64 + mi * 16 + fq * 4;

    if (J.bmode != 0) {       // packed v-projection: bias-add, bf16 out
#pragma unroll
      for (int ni = 0; ni < 4; ni++) {
        const int col = bcol + wn * 64 + ni * 16 + fr;
        const float bc = (J.bmode == 1) ? J.bias[col] : 0.f;
#pragma unroll
        for (int r = 0; r < 4; r++) {
          const int row = rbase + r;
          float v = acc[mi][ni][r] + ((J.bmode == 2) ? J.bias[row] : bc);
          Cb[cB + (long)row * J.ldc + col] = f2b(v);
        }
      }
    } else {                  // scores: exp + row sums
      float rs[4] = {0.f, 0.f, 0.f, 0.f};
#pragma unroll
      for (int ni = 0; ni < 4; ni++) {
        const int col = bcol + wn * 64 + ni * 16 + fr;
#pragma unroll
        for (int r = 0; r < 4; r++) {
          const int row = rbase + r;
          float v = acc[mi][ni][r] * J.scale + maskB[(long)row * J.ldM + col];
          v = __expf(v);
          Cb[cB + (long)row * J.ldc + col] = f2b(v);
          rs[r] += v;
        }
      }
#pragma unroll
      for (int off = 1; off < 16; off <<= 1) {
#pragma unroll
        for (int r = 0; r < 4; r++) rs[r] += __shfl_xor(rs[r], off, 64);
      }
      if (fr == 0) {
#pragma unroll
        for (int r = 0; r < 4; r++) atomicAdd(&sB[rbase + r], rs[r]);
      }
    }
  }
#undef STAGE16
}

// ------------- gemmJ: 8-wave bf16 GEMM (PV), R8-proven ------------------
// MODE 2: f32 out * (1/sRow[row]).
template <int NFRAG, int MODE>
__global__ __launch_bounds__(512, 2) void gemmJ(Job j0, Job j1, Job j2,
                                                int b0, int b1) {
  constexpr int BN = NFRAG * 64;
  constexpr int ASLOT = 256 * 64;
  constexpr int BSLOT = BN * 64;
  constexpr int SLOT = ASLOT + BSLOT;
  constexpr int CH = SLOT / 1024;
  constexpr int GPW = CH / 8;
  __shared__ __align__(16) char lds[4 * SLOT];

  const int nwg = gridDim.x;
  const int hw = blockIdx.x;
  int g = (hw & 7) * (nwg >> 3) + (hw >> 3);
  const Job J = (g < b0) ? j0 : (g < b1) ? j1 : j2;
  g -= (g < b0) ? 0 : (g < b1) ? b0 : b1;

  const int batch = g / J.tilesMN;
  const int tt = g - batch * J.tilesMN;
  const int tm = tt / J.tilesN, tn = tt - tm * J.tilesN;
  const int brow = tm << 8, bcol = tn * BN;

  const int tid = threadIdx.x;
  const int lane = tid & 63, w = tid >> 6;
  const int wm = w >> 2, wn = w & 3;
  const int fr = lane & 15, fq = lane >> 4;

  const unsigned short* Ab = J.A + (long)batch * J.sAb;
  const unsigned short* Bb = J.B + (long)batch * J.sBb;

  const unsigned short* gsrc[GPW];
  int ldsdst[GPW];
#pragma unroll
  for (int i = 0; i < GPW; i++) {
    const int c = w + i * 8;
    const bool isA = (c < 16);
    const int cc = isA ? c : c - 16;
    const int roff = cc * 1024 + lane * 16;
    const int L = roff ^ (((roff >> 7) & 7) << 4);
    const int row = L >> 6, colb = L & 63;
    gsrc[i] = (isA ? (Ab + (long)(brow + row) * J.lda)
                   : (Bb + (long)(bcol + row) * J.ldb)) + (colb >> 1);
    ldsdst[i] = (isA ? 0 : ASLOT) + cc * 1024;
  }

  int offA[8], offB[NFRAG];
#pragma unroll
  for (int mi = 0; mi < 8; mi++) {
    const int oa = (wm * 128 + mi * 16 + fr) * 64 + fq * 16;
    offA[mi] = oa ^ (((oa >> 7) & 7) << 4);
  }
#pragma unroll
  for (int ni = 0; ni < NFRAG; ni++) {
    const int ob = (wn * (NFRAG * 16) + ni * 16 + fr) * 64 + fq * 16;
    offB[ni] = ASLOT + (ob ^ (((ob >> 7) & 7) << 4));
  }

  f32x4 acc[8][NFRAG];
#pragma unroll
  for (int mi = 0; mi < 8; mi++)
#pragma unroll
    for (int ni = 0; ni < NFRAG; ni++) acc[mi][ni] = (f32x4){0.f, 0.f, 0.f, 0.f};

  const int NT = J.K >> 5;

#define STAGE(kt) { \
  char* const sb_ = lds + ((kt) & 3) * SLOT; \
  _Pragma("unroll") \
  for (int i_ = 0; i_ < GPW; i_++) \
    gload_lds16(gsrc[i_] + (long)(kt) * 32, sb_ + ldsdst[i_]); }

  STAGE(0);
  STAGE(1);
  waitvm<GPW>();
  __builtin_amdgcn_s_barrier();

  for (int t = 0; t < NT; ++t) {
    const char* sb = lds + (t & 3) * SLOT;
    if (t + 2 < NT) STAGE(t + 2);

    s8v bf[NFRAG], af[4];
#pragma unroll
    for (int ni = 0; ni < NFRAG; ni++) bf[ni] = *(const s8v*)(sb + offB[ni]);
#pragma unroll
    for (int mi = 0; mi < 4; mi++) af[mi] = *(const s8v*)(sb + offA[mi]);
    __builtin_amdgcn_s_setprio(1);
#pragma unroll
    for (int mi = 0; mi < 4; mi++)
#pragma unroll
      for (int ni = 0; ni < NFRAG; ni++)
        acc[mi][ni] = __builtin_amdgcn_mfma_f32_16x16x32_bf16(
            af[mi], bf[ni], acc[mi][ni], 0, 0, 0);
    __builtin_amdgcn_s_setprio(0);
#pragma unroll
    for (int mi = 0; mi < 4; mi++) af[mi] = *(const s8v*)(sb + offA[4 + mi]);
    __builtin_amdgcn_s_setprio(1);
#pragma unroll
    for (int mi = 0; mi < 4; mi++)
#pragma unroll
      for (int ni = 0; ni < NFRAG; ni++)
        acc[4 + mi][ni] = __builtin_amdgcn_mfma_f32_16x16x32_bf16(
            af[mi], bf[ni], acc[4 + mi][ni], 0, 0, 0);
    __builtin_amdgcn_s_setprio(0);

    if (t + 1 < NT) {
      if (t + 2 < NT) waitvm<GPW>();
      else            waitvm<0>();
      __builtin_amdgcn_s_barrier();
    }
  }

  float* Cf = (float*)J.C;
  const long cB = (long)batch * J.sCb;
  float* sB = J.sRow + batch * 2048;

#pragma unroll
  for (int mi = 0; mi < 8; mi++) {
    const int rbase = brow + wm * 128 + mi * 16 + fq * 4;
    float inv[4];
#pragma unroll
    for (int r = 0; r < 4; r++) inv[r] = 1.0f / sB[rbase + r];
#pragma unroll
    for (int ni = 0; ni < NFRAG; ni++) {
      const int col = bcol + wn * (NFRAG * 16) + ni * 16 + fr;
#pragma unroll
      for (int r = 0; r < 4; r++) {
        const int row = rbase + r;
        Cf[cB + (long)row * J.ldc + col] = acc[mi][ni][r] * inv[r];
      }
    }
  }
#undef STAGE
}

// cvt v (768 blocks) + Wv (128 blocks) -> bf16; zero sRow[8192] (8 blocks,
// grid-stride).
__global__ __launch_bounds__(256) void cvtW(
    const float* v, unsigned short* xv,
    const float* Wv, unsigned short* Wvb, float* sz) {
  int bid = blockIdx.x;
  if (bid >= 896) {
    for (int i = (bid - 896) * 256 + threadIdx.x; i < 8192; i += 2048)
      sz[i] = 0.f;
    return;
  }
  const float* src; unsigned short* dst; long n8; int lb, nb;
  if (bid < 768) { src = v;  dst = xv;  n8 = 1048576; lb = bid;       nb = 768; }
  else           { src = Wv; dst = Wvb; n8 = 131072;  lb = bid - 768; nb = 128; }
  const long stride = (long)nb * 256;
  for (long i = (long)lb * 256 + threadIdx.x; i < n8; i += stride) {
    const float* p = src + i * 8;
    f32x4 va = *(const f32x4*)p;
    f32x4 vb = *(const f32x4*)(p + 4);
    s8v o;
    o[0] = (short)f2b(va[0]); o[1] = (short)f2b(va[1]);
    o[2] = (short)f2b(va[2]); o[3] = (short)f2b(va[3]);
    o[4] = (short)f2b(vb[0]); o[5] = (short)f2b(vb[1]);
    o[6] = (short)f2b(vb[2]); o[7] = (short)f2b(vb[3]);
    *(s8v*)(dst + i * 8) = o;
  }
}

extern "C" void kernel_launch(void* const* d_in, const int* in_sizes, int n_in,
                              void* d_out, int out_size, void* d_ws, size_t ws_size,
                              hipStream_t stream) {
  const float* q    = (const float*)d_in[0];
  const float* k    = (const float*)d_in[1];
  const float* v    = (const float*)d_in[2];
  const float* mask = (const float*)d_in[3];
  const float* Wq   = (const float*)d_in[4];
  const float* bq   = (const float*)d_in[5];
  const float* Wk   = (const float*)d_in[6];
  const float* bk   = (const float*)d_in[7];
  const float* Wv   = (const float*)d_in[8];
  const float* bv   = (const float*)d_in[9];
  float* out = (float*)d_out;

  const size_t MB = 1ull << 20;
  if (ws_size < 134 * MB) return;
  char* ws = (char*)d_ws;
  unsigned short* qb  = (unsigned short*)(ws + 0 * MB);
  unsigned short* kb  = (unsigned short*)(ws + 16 * MB);
  unsigned short* vT  = (unsigned short*)(ws + 32 * MB);
  float*          sRw = (float*)(ws + 48 * MB);           // 32KB
  unsigned short* Sb  = (unsigned short*)(ws + 80 * MB);  // 32MB
  unsigned short* xv  = (unsigned short*)(ws + 112 * MB);
  unsigned short* Wvb = (unsigned short*)(ws + 132 * MB);

  // L0: convert v + Wv to bf16, zero sRow[8192]
  cvtW<<<904, 256, 0, stream>>>(v, xv, Wv, Wvb, sRw);

  // L1: q,k projections from raw f32 — 256 blocks = 1 generation.
  JobF fq = { q, Wq, qb, bq, 0, 0, 0, 1024, 1024, 1024, 4, 128, 1 };
  JobF fk = { k, Wk, kb, bk, 0, 0, 0, 1024, 1024, 1024, 4, 128, 1 };
  gemmF<<<256, 512, 0, stream>>>(fq, fk, fk, 128, 256);

  // L2: 16-wave scores (256 blocks, bmode=0) + v-proj (128, bmode=2).
  Job js = { qb, kb, (void*)Sb, nullptr, mask, sRw,
             2048L * 1024, 2048L * 1024, 2048L * 2048, 2048L * 2048,
             1024, 1024, 2048, 2048, 1024, 8, 64, 0.03125f, 0 };
  Job jv = { Wvb, xv, (void*)vT, bv, mask, sRw,
             0, 2048L * 1024, 1024L * 2048, 0,
             1024, 1024, 2048, 0, 1024, 8, 32, 1.0f, 2 };
  gemmJ16<<<384, 1024, 0, stream>>>(js, js, jv, 256, 256);

  // L3: PV: out = (E . vT^T) / sRow; 8 tm x 8 tn x 4 = 256 blocks, K=2048.
  Job jp = { Sb, vT, (void*)out, nullptr, nullptr, sRw,
             2048L * 2048, 1024L * 2048, 2048L * 1024, 0,
             2048, 2048, 1024, 0, 2048, 8, 64, 1.0f, 0 };
  gemmJ<2, 2><<<256, 512, 0, stream>>>(jp, jp, jp, 256, 256);
}